// Round 16
// baseline (145.963 us; speedup 1.0000x reference)
//
#include <hip/hip_runtime.h>
#include <hip/hip_bf16.h>
#include <math.h>

namespace {

constexpr int T  = 2048;
constexpr int HD = 64;
constexpr float EPS = 1.1920929e-07f;
// SCALE * log2(e), folded into q at proj_q write time -> attn softmax runs in exp2 domain
constexpr float PS = 0.125f * 1.44269504f;

// bf16 weight pool offsets (in elements)
constexpr int OFF_DQ  = 0;       // 512*64
constexpr int OFF_UQ  = 32768;   // 64*512
constexpr int OFF_DKV = 65536;   // 1024*64
constexpr int OFF_UKV = 131072;  // 128*1024
constexpr int OFF_QR  = 262144;  // 64*64
constexpr int OFF_KR  = 266240;  // 64*64
constexpr int OFF_O   = 270336;  // 64*64
constexpr int W_TOTAL = 274432;

typedef __attribute__((ext_vector_type(8))) short bf8v;  // 8 bf16 (4 VGPR)
typedef __attribute__((ext_vector_type(4))) float f4v;   // MFMA C/D

#define MFMA16(a, b, c) __builtin_amdgcn_mfma_f32_16x16x32_bf16((a), (b), (c), 0, 0, 0)

// full-strength barrier for raw s_barrier use (rule #18 class): compiler
// memory fences both sides so gload_lds issues can't be hoisted across.
#define HARD_BARRIER()                                   \
  do {                                                   \
    asm volatile("" ::: "memory");                       \
    __builtin_amdgcn_s_barrier();                        \
    asm volatile("" ::: "memory");                       \
    __builtin_amdgcn_sched_barrier(0);                   \
  } while (0)

__device__ __forceinline__ short f2bf(float f) {
  union { float f; unsigned u; } v; v.f = f;
  unsigned r = v.u + 0x7FFFu + ((v.u >> 16) & 1u); // RNE
  return (short)(r >> 16);
}

__device__ __forceinline__ f4v z4() { f4v z = {0.f, 0.f, 0.f, 0.f}; return z; }

// XOR swizzles: spread row-strided b128 accesses across banks (m214 pattern)
__device__ __forceinline__ int swz128(int b) { return b ^ (((b >> 7) & 7) << 4); }
__device__ __forceinline__ int swz256(int b) { return b ^ (((b >> 8) & 7) << 4); }

__device__ __forceinline__ bf8v ldA128(const short* lds, int row, int k) {
  return *(const bf8v*)((const char*)lds + swz128(row * 128 + k * 2));
}
__device__ __forceinline__ bf8v ldA256(const short* lds, int row, int k) {
  return *(const bf8v*)((const char*)lds + swz256(row * 256 + k * 2));
}

// scatter a 16x16 D-fragment (col=lane&15, row=(lane>>4)*4+r) as bf16 into LDS
__device__ __forceinline__ void scat128(short* lds, int row0, int lane, int nt, f4v v) {
  int col = nt * 16 + (lane & 15);
  int r0 = row0 + ((lane >> 4) << 2);
#pragma unroll
  for (int r = 0; r < 4; ++r)
    *(short*)((char*)lds + swz128((r0 + r) * 128 + col * 2)) = f2bf(v[r]);
}
__device__ __forceinline__ void scat256(short* lds, int row0, int lane, int col, f4v v) {
  int r0 = row0 + ((lane >> 4) << 2);
#pragma unroll
  for (int r = 0; r < 4; ++r)
    *(short*)((char*)lds + swz256((r0 + r) * 256 + col * 2)) = f2bf(v[r]);
}

// async global->LDS, 16B per lane; LDS dest wave-uniform base + lane*16
__device__ __forceinline__ void gload_lds16(const void* g, void* l) {
  __builtin_amdgcn_global_load_lds(
      (const __attribute__((address_space(1))) void*)g,
      (__attribute__((address_space(3))) void*)l, 16, 0, 0);
}

// ---------------------------------------------------------------------------
// conversions
// ---------------------------------------------------------------------------
__global__ __launch_bounds__(256) void cvt_x_kernel(const float* __restrict__ x,
                                                    short* __restrict__ xb) {
  int i = (blockIdx.x * 256 + threadIdx.x) * 4; // over x linear (B,T,D)
  float4 v = *(const float4*)(x + i);
  int d = i & 1023, t = (i >> 10) & 2047, b = i >> 21;
  int h = d >> 6, dd = d & 63;
  short4 o;
  o.x = f2bf(v.x); o.y = f2bf(v.y); o.z = f2bf(v.z); o.w = f2bf(v.w);
  *(short4*)(xb + ((((size_t)b * 16 + h) * T + t) * 64 + dd)) = o;
}

__global__ __launch_bounds__(256) void cvt_w_kernel(
    const float* __restrict__ W_DQ, const float* __restrict__ W_UQ,
    const float* __restrict__ W_DKV, const float* __restrict__ W_UKV,
    const float* __restrict__ W_QR, const float* __restrict__ W_KR,
    const float* __restrict__ W_O, short* __restrict__ wb) {
  int i = blockIdx.x * 256 + threadIdx.x;
  const float* src; int off;
  if      (i < 32768)  { src = W_DQ;  off = 0; }
  else if (i < 65536)  { src = W_UQ;  off = 32768; }
  else if (i < 131072) { src = W_DKV; off = 65536; }
  else if (i < 262144) { src = W_UKV; off = 131072; }
  else if (i < 266240) { src = W_QR;  off = 262144; }
  else if (i < 270336) { src = W_KR;  off = 266240; }
  else                 { src = W_O;   off = 270336; }
  wb[i] = f2bf(src[i - off]);
}

// ---------------------------------------------------------------------------
// proj_fused: one launch, two block variants running CONCURRENTLY.
//   blockIdx.y <  32: proj_kv for bh = y      (longer; dispatched first)
//   blockIdx.y >= 32: proj_q  for bh = y - 32
// Shared 80KB LDS block, per-variant aliasing via NAMED pointers + ternary
// selection (pointer ARRAYS into LDS fail gfx950 codegen: addrspacecast in
// static initializer — round-15 compile error). Bodies = proven round-10 code.
// ---------------------------------------------------------------------------
__global__ __launch_bounds__(256) void proj_fused(
    const short* __restrict__ xb, const short* __restrict__ wb,
    const float* __restrict__ qnw, const float* __restrict__ knw,
    short* __restrict__ qb, short* __restrict__ kb, short* __restrict__ vtg) {
  __shared__ __attribute__((aligned(16))) short SM[40960]; // 80KB

  const int tid = threadIdx.x, lane = tid & 63, w = tid >> 6;
  const int c16 = lane & 15;
  const int g4 = lane >> 4;
  const int koff = g4 << 3;
  const int rg4 = g4 << 2;
  const int t0 = blockIdx.x * 128;
  const bool iskv = blockIdx.y < 32;
  const int bh = iskv ? blockIdx.y : blockIdx.y - 32;

  if (iskv) {
    // ---- proj_kv layout (element offsets): Xs=0, Wd0=8192, Wd1=12288,
    //      Wu0=16384, Wu1=24576 (Ko spans 16384..32768), Cs=32768
    short* const Xs  = SM;
    short* const Wd0 = SM + 8192;
    short* const Wd1 = SM + 12288;
    short* const Wu0 = SM + 16384;
    short* const Wu1 = SM + 24576;
    short* const Cs  = SM + 32768;

    auto stageWd = [&](int lc) {
      const char* src = (const char*)(wb + OFF_DKV + lc * 64 * 64);
      char* dst = (char*)((lc & 1) ? Wd1 : Wd0);
#pragma unroll
      for (int p = 0; p < 2; ++p) {
        const int base = p * 256 + w * 64;
        gload_lds16(src + swz128((base + lane) * 16), dst + base * 16);
      }
    };
    auto stageWu = [&](int lc) {
      const char* src = (const char*)(wb + OFF_UKV + lc * 64);
      char* dst = (char*)((lc & 1) ? Wu1 : Wu0);
#pragma unroll
      for (int p = 0; p < 4; ++p) {
        const int base = p * 256 + w * 64;
        const int lb = swz128((base + lane) * 16);
        gload_lds16(src + (size_t)(lb >> 7) * 2048 + (lb & 127), dst + base * 16);
      }
    };

    {
      const char* src = (const char*)(xb + ((size_t)bh * T + t0) * 64);
#pragma unroll
      for (int p = 0; p < 4; ++p) {
        const int base = p * 256 + w * 64;
        gload_lds16(src + swz128((base + lane) * 16), (char*)Xs + base * 16);
      }
    }
    stageWd(0);
    stageWu(0);
    __syncthreads();

    f4v acc[2][8];
#pragma unroll
    for (int rg = 0; rg < 2; ++rg)
#pragma unroll
      for (int nt = 0; nt < 8; ++nt) acc[rg][nt] = z4();

    for (int lc = 0; lc < 16; ++lc) {
      if (lc < 15) { stageWd(lc + 1); stageWu(lc + 1); }
      else { // prefetch W_KR into Wd0 for the epilogue
        const char* src = (const char*)(wb + OFF_KR);
        char* dst = (char*)Wd0;
#pragma unroll
        for (int p = 0; p < 2; ++p) {
          const int base = p * 256 + w * 64;
          gload_lds16(src + swz128((base + lane) * 16), dst + base * 16);
        }
      }
      const short* Wdc = (lc & 1) ? Wd1 : Wd0;
      const short* Wuc = (lc & 1) ? Wu1 : Wu0;

      f4v cc[2][4];
#pragma unroll
      for (int rg = 0; rg < 2; ++rg)
#pragma unroll
        for (int nt = 0; nt < 4; ++nt) cc[rg][nt] = z4();
#pragma unroll
      for (int rg = 0; rg < 2; ++rg)
#pragma unroll
        for (int ks = 0; ks < 2; ++ks) {
          bf8v a = ldA128(Xs, w * 32 + rg * 16 + c16, ks * 32 + koff);
#pragma unroll
          for (int nt = 0; nt < 4; ++nt) {
            bf8v b = ldA128(Wdc, nt * 16 + c16, ks * 32 + koff);
            cc[rg][nt] = MFMA16(a, b, cc[rg][nt]);
          }
        }
#pragma unroll
      for (int rg = 0; rg < 2; ++rg)
#pragma unroll
        for (int nt = 0; nt < 4; ++nt)
          scat128(Cs, w * 32 + rg * 16, lane, nt, cc[rg][nt]);
#pragma unroll
      for (int rg = 0; rg < 2; ++rg)
#pragma unroll
        for (int ks = 0; ks < 2; ++ks) {
          bf8v a = ldA128(Cs, w * 32 + rg * 16 + c16, ks * 32 + koff);
#pragma unroll
          for (int nt = 0; nt < 8; ++nt) {
            bf8v b = ldA128(Wuc, nt * 16 + c16, ks * 32 + koff);
            acc[rg][nt] = MFMA16(a, b, acc[rg][nt]);
          }
        }
      __syncthreads();
    }

    float w4[4];
#pragma unroll
    for (int nt = 0; nt < 4; ++nt) w4[nt] = knw[nt * 16 + c16];
#pragma unroll
    for (int rg = 0; rg < 2; ++rg)
#pragma unroll
      for (int r = 0; r < 4; ++r) {
        float ss = 0.f;
#pragma unroll
        for (int nt = 0; nt < 4; ++nt) ss += acc[rg][nt][r] * acc[rg][nt][r];
        ss += __shfl_xor(ss, 1, 16); ss += __shfl_xor(ss, 2, 16);
        ss += __shfl_xor(ss, 4, 16); ss += __shfl_xor(ss, 8, 16);
        float inv = rsqrtf(ss * (1.f / 64.f) + EPS);
#pragma unroll
        for (int nt = 0; nt < 4; ++nt) acc[rg][nt][r] *= inv * w4[nt];
      }

    short* const Ko = Wu0; // [128][128] 256B rows, spans Wu0..Wu1 (32KB)
#pragma unroll
    for (int rg = 0; rg < 2; ++rg)
#pragma unroll
      for (int nt = 0; nt < 4; ++nt)
        scat256(Ko, w * 32 + rg * 16, lane, nt * 16 + c16, acc[rg][nt]);

    // Vt = Cs region as [64 d][128 t] (256B rows): v transposed
#pragma unroll
    for (int rg = 0; rg < 2; ++rg)
#pragma unroll
      for (int nt = 0; nt < 4; ++nt) {
        const int d = nt * 16 + c16;
        const int tc0 = w * 32 + rg * 16 + rg4;
#pragma unroll
        for (int r = 0; r < 4; ++r)
          *(short*)((char*)Cs + swz256(d * 256 + (tc0 + r) * 2)) =
              f2bf(acc[rg][4 + nt][r]);
      }

    // k_r = xh @ W_KR^T (Wd0 landed at last loop barrier)
    f4v kr[2][4];
#pragma unroll
    for (int rg = 0; rg < 2; ++rg)
#pragma unroll
      for (int nt = 0; nt < 4; ++nt) kr[rg][nt] = z4();
#pragma unroll
    for (int rg = 0; rg < 2; ++rg)
#pragma unroll
      for (int ks = 0; ks < 2; ++ks) {
        bf8v a = ldA128(Xs, w * 32 + rg * 16 + c16, ks * 32 + koff);
#pragma unroll
        for (int nt = 0; nt < 4; ++nt) {
          bf8v b = ldA128(Wd0, nt * 16 + c16, ks * 32 + koff);
          kr[rg][nt] = MFMA16(a, b, kr[rg][nt]);
        }
      }
#pragma unroll
    for (int rg = 0; rg < 2; ++rg)
#pragma unroll
      for (int nt = 0; nt < 4; ++nt)
        scat256(Ko, w * 32 + rg * 16, lane, 64 + nt * 16 + c16, kr[rg][nt]);
    __syncthreads();

    short* kdst = kb + ((size_t)bh * T + t0) * 128;
#pragma unroll
    for (int p = 0; p < 8; ++p) {
      int ci = tid + p * 256;
      int r = ci >> 4, c = (ci & 15) << 3;
      *(bf8v*)(kdst + (size_t)r * 128 + c) =
          *(const bf8v*)((const char*)Ko + swz256(ci * 16));
    }
#pragma unroll
    for (int p = 0; p < 4; ++p) {
      int ci = tid + p * 256;
      int d = ci >> 4, c = (ci & 15) << 3;
      *(bf8v*)(vtg + ((size_t)bh * 64 + d) * T + t0 + c) =
          *(const bf8v*)((const char*)Cs + swz256(ci * 16));
    }
  } else {
    // ---- proj_q layout (element offsets): Xs=0, Wd0=8192, Wd1=12288,
    //      Wu0=16384, Wu1=20480, Cs=24576
    short* const Xs  = SM;
    short* const Wd0 = SM + 8192;
    short* const Wd1 = SM + 12288;
    short* const Wu0 = SM + 16384;
    short* const Wu1 = SM + 20480;
    short* const Cs  = SM + 24576;

    auto stageWd = [&](int lc) {
      const char* src = (const char*)(wb + OFF_DQ + lc * 64 * 64);
      char* dst = (char*)((lc & 1) ? Wd1 : Wd0);
#pragma unroll
      for (int p = 0; p < 2; ++p) {
        const int base = p * 256 + w * 64;
        gload_lds16(src + swz128((base + lane) * 16), dst + base * 16);
      }
    };
    auto stageWu = [&](int lc) {
      const char* src = (const char*)(wb + OFF_UQ + lc * 64);
      char* dst = (char*)((lc & 1) ? Wu1 : Wu0);
#pragma unroll
      for (int p = 0; p < 2; ++p) {
        const int base = p * 256 + w * 64;
        const int lb = swz128((base + lane) * 16);
        gload_lds16(src + (size_t)(lb >> 7) * 1024 + (lb & 127), dst + base * 16);
      }
    };

    {
      const char* src = (const char*)(xb + ((size_t)bh * T + t0) * 64);
#pragma unroll
      for (int p = 0; p < 4; ++p) {
        const int base = p * 256 + w * 64;
        gload_lds16(src + swz128((base + lane) * 16), (char*)Xs + base * 16);
      }
    }
    stageWd(0);
    stageWu(0);
    __syncthreads();

    f4v acc[2][4];
#pragma unroll
    for (int rg = 0; rg < 2; ++rg)
#pragma unroll
      for (int nt = 0; nt < 4; ++nt) acc[rg][nt] = z4();

    for (int lc = 0; lc < 8; ++lc) {
      if (lc < 7) { stageWd(lc + 1); stageWu(lc + 1); }
      else { // prefetch W_QR into Wd0 for the epilogue
        const char* src = (const char*)(wb + OFF_QR);
        char* dst = (char*)Wd0;
#pragma unroll
        for (int p = 0; p < 2; ++p) {
          const int base = p * 256 + w * 64;
          gload_lds16(src + swz128((base + lane) * 16), dst + base * 16);
        }
      }
      const short* Wdc = (lc & 1) ? Wd1 : Wd0;
      const short* Wuc = (lc & 1) ? Wu1 : Wu0;

      f4v cc[2][4];
#pragma unroll
      for (int rg = 0; rg < 2; ++rg)
#pragma unroll
        for (int nt = 0; nt < 4; ++nt) cc[rg][nt] = z4();
#pragma unroll
      for (int rg = 0; rg < 2; ++rg)
#pragma unroll
        for (int ks = 0; ks < 2; ++ks) {
          bf8v a = ldA128(Xs, w * 32 + rg * 16 + c16, ks * 32 + koff);
#pragma unroll
          for (int nt = 0; nt < 4; ++nt) {
            bf8v b = ldA128(Wdc, nt * 16 + c16, ks * 32 + koff);
            cc[rg][nt] = MFMA16(a, b, cc[rg][nt]);
          }
        }
#pragma unroll
      for (int rg = 0; rg < 2; ++rg)
#pragma unroll
        for (int nt = 0; nt < 4; ++nt)
          scat128(Cs, w * 32 + rg * 16, lane, nt, cc[rg][nt]);
#pragma unroll
      for (int rg = 0; rg < 2; ++rg)
#pragma unroll
        for (int ks = 0; ks < 2; ++ks) {
          bf8v a = ldA128(Cs, w * 32 + rg * 16 + c16, ks * 32 + koff);
#pragma unroll
          for (int nt = 0; nt < 4; ++nt) {
            bf8v b = ldA128(Wuc, nt * 16 + c16, ks * 32 + koff);
            acc[rg][nt] = MFMA16(a, b, acc[rg][nt]);
          }
        }
      __syncthreads();
    }

    float w4[4];
#pragma unroll
    for (int nt = 0; nt < 4; ++nt) w4[nt] = qnw[nt * 16 + c16] * PS;
#pragma unroll
    for (int rg = 0; rg < 2; ++rg)
#pragma unroll
      for (int r = 0; r < 4; ++r) {
        float ss = 0.f;
#pragma unroll
        for (int nt = 0; nt < 4; ++nt) ss += acc[rg][nt][r] * acc[rg][nt][r];
        ss += __shfl_xor(ss, 1, 16); ss += __shfl_xor(ss, 2, 16);
        ss += __shfl_xor(ss, 4, 16); ss += __shfl_xor(ss, 8, 16);
        float inv = rsqrtf(ss * (1.f / 64.f) + EPS); // PS lives in w4 only
#pragma unroll
        for (int nt = 0; nt < 4; ++nt) acc[rg][nt][r] *= inv * w4[nt];
      }

#pragma unroll
    for (int rg = 0; rg < 2; ++rg)
#pragma unroll
      for (int nt = 0; nt < 4; ++nt)
        scat128(Cs, w * 32 + rg * 16, lane, nt, acc[rg][nt]);

    f4v qr[2][4];
#pragma unroll
    for (int rg = 0; rg < 2; ++rg)
#pragma unroll
      for (int nt = 0; nt < 4; ++nt) qr[rg][nt] = z4();
#pragma unroll
    for (int rg = 0; rg < 2; ++rg)
#pragma unroll
      for (int ks = 0; ks < 2; ++ks) {
        bf8v a = ldA128(Cs, w * 32 + rg * 16 + c16, ks * 32 + koff);
#pragma unroll
        for (int nt = 0; nt < 4; ++nt) {
          bf8v b = ldA128(Wd0, nt * 16 + c16, ks * 32 + koff);
          qr[rg][nt] = MFMA16(a, b, qr[rg][nt]);
        }
      }
#pragma unroll
    for (int rg = 0; rg < 2; ++rg)
#pragma unroll
      for (int nt = 0; nt < 4; ++nt)
        scat128(Xs, w * 32 + rg * 16, lane, nt, qr[rg][nt]);
    __syncthreads();

    short* qdst = qb + ((size_t)bh * T + t0) * 128;
#pragma unroll
    for (int p = 0; p < 4; ++p) {
      int ci = tid + p * 256;
      int r = ci >> 3, c = (ci & 7) << 3;
      *(bf8v*)(qdst + (size_t)r * 128 + c) =
          *(const bf8v*)((const char*)Cs + swz128(ci * 16));
      *(bf8v*)(qdst + (size_t)r * 128 + 64 + c) =
          *(const bf8v*)((const char*)Xs + swz128(ci * 16));
    }
  }
}

// ---------------------------------------------------------------------------
// attn v7c (round-10 verbatim — best measured: 75us): depth-2 counted-vmcnt
// pipeline, paired q-tiles (i,31-i), coop K/V staging, HARD_BARRIERs.
// ---------------------------------------------------------------------------
__global__ __launch_bounds__(256) void attn_mfma(
    const short* __restrict__ qb, const short* __restrict__ kb,
    const short* __restrict__ vtg, const short* __restrict__ wb,
    float* __restrict__ out) {
  __shared__ __attribute__((aligned(16))) short Ks[3][64 * 128]; // swz256, 16KB ea
  __shared__ __attribute__((aligned(16))) short Vs[2][64 * 64];  // swz128, 8KB ea
  __shared__ __attribute__((aligned(16))) short Ps[64 * 64];     // swz128, 8KB

  const int tid = threadIdx.x, lane = tid & 63, w = tid >> 6;
  const int lin = blockIdx.y * 16 + blockIdx.x; // [0,512)
  const int xcd = lin & 7, slot = lin >> 3;     // slot [0,64)
  const int bh = xcd + 8 * (slot >> 4);         // 4 bh per XCD -> KV L2-resident
  const int px = slot & 15;
  const int qtA = px, qtB = 31 - px;
  const int cntA = qtA + 1;
  const int NT = 33;

  const int b = bh >> 4, h = bh & 15;
  const int c16 = lane & 15;
  const int g4 = lane >> 4;
  const int koff = g4 << 3;
  const int rg4 = g4 << 2;
  const int lbase = lane & 48;

  const short* kbh = kb + (size_t)bh * T * 128;
  const short* vbh = vtg + (size_t)bh * 64 * T;

  bf8v aqA[4], aqB[4], bwo[2][4];
  {
    const short* qA = qb + ((size_t)bh * T + qtA * 64 + w * 16 + c16) * 128;
    const short* qB = qb + ((size_t)bh * T + qtB * 64 + w * 16 + c16) * 128;
#pragma unroll
    for (int ks = 0; ks < 4; ++ks) {
      aqA[ks] = *(const bf8v*)(qA + ks * 32 + koff);
      aqB[ks] = *(const bf8v*)(qB + ks * 32 + koff);
    }
#pragma unroll
    for (int ks = 0; ks < 2; ++ks)
#pragma unroll
      for (int nt = 0; nt < 4; ++nt)
        bwo[ks][nt] = *(const bf8v*)(wb + OFF_O + (size_t)(nt * 16 + c16) * 64 +
                                     ks * 32 + koff);
  }

  auto ktile = [&](int gg) { return (gg < NT) ? ((gg < cntA) ? gg : gg - cntA) : 0; };

  auto stageK = [&](int gg) { // 4 gload_lds per wave
    const int jt = ktile(gg);
    const char* src = (const char*)(kbh + jt * 64 * 128);
    char* dst = (char*)&Ks[gg % 3][0];
#pragma unroll
    for (int p = 0; p < 4; ++p) {
      const int base = p * 256 + w * 64;
      gload_lds16(src + swz256((base + lane) * 16), dst + base * 16);
    }
  };
  auto stageV = [&](int gg) { // 2 gload_lds per wave
    const int jt = ktile(gg);
    char* dst = (char*)&Vs[gg & 1][0];
#pragma unroll
    for (int p = 0; p < 2; ++p) {
      const int base = p * 256 + w * 64;
      const int tb = swz128((base + lane) * 16);
      const int r = tb >> 7, cb = tb & 127;
      gload_lds16((const char*)vbh + ((size_t)r * T + jt * 64) * 2 + cb,
                  dst + base * 16);
    }
  };

  stageK(0);
  stageK(1);
  stageV(0);
  asm volatile("s_waitcnt vmcnt(6)" ::: "memory");
  HARD_BARRIER();

  int gg = 0;
  float* obase = out + (size_t)b * T * 1024 + h * 64;

  auto run_seg = [&](const int qt, const bf8v(&aq)[4]) {
    const int t0 = qt * 64;
    const int lrow = w * 16 + rg4;
    const int qglob = t0 + w * 16 + c16;

    f4v ctx[4];
    float m = -INFINITY, l = 0.f;
#pragma unroll
    for (int nt = 0; nt < 4; ++nt) ctx[nt] = z4();

    for (int jt = 0; jt <= qt; ++jt, ++gg) {
      const short* Kb = &Ks[gg % 3][0];
      const short* Vb = &Vs[gg & 1][0];
      stageK(gg + 2);
      stageV(gg + 1);

      const int j0 = jt * 64;
      const bool diag = (jt == qt);

      f4v s[4];
#pragma unroll
      for (int nt = 0; nt < 4; ++nt) s[nt] = z4();
#pragma unroll
      for (int ks = 0; ks < 4; ++ks) {
#pragma unroll
        for (int nt = 0; nt < 4; ++nt) {
          bf8v bk = ldA256(Kb, nt * 16 + c16, ks * 32 + koff);
          s[nt] = MFMA16(bk, aq[ks], s[nt]); // A=K, B=Q (swapped)
        }
      }

      if (diag) {
#pragma unroll
        for (int nt = 0; nt < 4; ++nt)
#pragma unroll
          for (int r = 0; r < 4; ++r)
            if (j0 + nt * 16 + rg4 + r > qglob) s[nt][r] = -INFINITY;
      }

      f4v mnt;
#pragma unroll
      for (int r = 0; r < 4; ++r)
        mnt[r] = fmaxf(fmaxf(s[0][r], s[1][r]), fmaxf(s[2][r], s[3][r]));
      float mx = fmaxf(fmaxf(mnt[0], mnt[1]), fmaxf(mnt[2], mnt[3]));
      mx = fmaxf(mx, __shfl_xor(mx, 16));
      mx = fmaxf(mx, __shfl_xor(mx, 32));

      if (__any(mx - m > 8.f)) {
        const float mn  = fmaxf(m, mx);
        const float scl = __builtin_amdgcn_exp2f(m - mn);
        l *= scl; m = mn;
        float sr[4];
#pragma unroll
        for (int r = 0; r < 4; ++r) sr[r] = __shfl(scl, lbase + rg4 + r);
#pragma unroll
        for (int nt = 0; nt < 4; ++nt)
#pragma unroll
          for (int r = 0; r < 4; ++r) ctx[nt][r] *= sr[r];
      }

#pragma unroll
      for (int nt = 0; nt < 4; ++nt)
#pragma unroll
        for (int r = 0; r < 4; ++r)
          s[nt][r] = __builtin_amdgcn_exp2f(s[nt][r] - m);
      f4v sv = s[0] + s[1] + s[2] + s[3];
      float rs = (sv[0] + sv[1]) + (sv[2] + sv[3]);
      rs += __shfl_xor(rs, 16);
      rs += __shfl_xor(rs, 32);
      l += rs;

      {
        char* prow = (char*)Ps;
        const int rbase = (w * 16 + c16) * 128 + koff;
#pragma unroll
        for (int nt = 0; nt < 4; ++nt) {
          __hip_bfloat162 h0 = __float22bfloat162_rn(make_float2(s[nt][0], s[nt][1]));
          __hip_bfloat162 h1 = __float22bfloat162_rn(make_float2(s[nt][2], s[nt][3]));
          uint2 d;
          d.x = *(unsigned int*)&h0;
          d.y = *(unsigned int*)&h1;
          *(uint2*)(prow + swz128(rbase + nt * 32)) = d;
        }
      }

      // drain prev tile's loads (leaves this tile's 6 in flight), then barrier
      // so ALL waves' V(gg) chunks are landed before any PV read
      asm volatile("s_waitcnt vmcnt(6)" ::: "memory");
      HARD_BARRIER();

#pragma unroll
      for (int ks = 0; ks < 2; ++ks) {
        bf8v pa = ldA128(Ps, w * 16 + c16, ks * 32 + koff);
#pragma unroll
        for (int nt = 0; nt < 4; ++nt) {
          bf8v vf = ldA128(Vb, nt * 16 + c16, ks * 32 + koff);
          ctx[nt] = MFMA16(pa, vf, ctx[nt]);
        }
      }

      HARD_BARRIER(); // buffer-reuse WAR fence
    }

    float linv[4];
#pragma unroll
    for (int r = 0; r < 4; ++r) linv[r] = 1.0f / __shfl(l, lbase + rg4 + r);
    f4v cn[4];
#pragma unroll
    for (int nt = 0; nt < 4; ++nt)
#pragma unroll
      for (int r = 0; r < 4; ++r) cn[nt][r] = ctx[nt][r] * linv[r];
#pragma unroll
    for (int nt = 0; nt < 4; ++nt) scat128(Ps, w * 16, lane, nt, cn[nt]);

    f4v o[4];
#pragma unroll
    for (int nt = 0; nt < 4; ++nt) o[nt] = z4();
#pragma unroll
    for (int ks = 0; ks < 2; ++ks) {
      bf8v pa = ldA128(Ps, w * 16 + c16, ks * 32 + koff);
#pragma unroll
      for (int nt = 0; nt < 4; ++nt) o[nt] = MFMA16(pa, bwo[ks][nt], o[nt]);
    }

#pragma unroll
    for (int nt = 0; nt < 4; ++nt) {
#pragma unroll
      for (int r = 0; r < 4; ++r)
        obase[(size_t)(t0 + lrow + r) * 1024 + nt * 16 + c16] = o[nt][r];
    }
  };

  run_seg(qtA, aqA);
  run_seg(qtB, aqB);
}

} // namespace

extern "C" void kernel_launch(void* const* d_in, const int* in_sizes, int n_in,
                              void* d_out, int out_size, void* d_ws, size_t ws_size,
                              hipStream_t stream) {
  (void)in_sizes; (void)n_in; (void)out_size; (void)ws_size;
  const float* x     = (const float*)d_in[0];
  const float* W_DQ  = (const float*)d_in[1];
  const float* W_UQ  = (const float*)d_in[2];
  const float* W_DKV = (const float*)d_in[3];
  const float* W_UKV = (const float*)d_in[4];
  const float* W_QR  = (const float*)d_in[5];
  const float* W_KR  = (const float*)d_in[6];
  const float* W_O   = (const float*)d_in[7];
  const float* qnw   = (const float*)d_in[8];
  const float* knw   = (const float*)d_in[9];
  float* out = (float*)d_out;

  short* ws = (short*)d_ws;
  short* xb  = ws;                          // 4,194,304
  short* qb  = ws + (size_t)4194304;        // 8,388,608
  short* kb  = ws + (size_t)12582912;       // 8,388,608
  short* vtg = ws + (size_t)20971520;       // 4,194,304
  short* wb  = ws + (size_t)25165824;       // 274,432

  cvt_x_kernel<<<4096, 256, 0, stream>>>(x, xb);
  cvt_w_kernel<<<W_TOTAL / 256, 256, 0, stream>>>(W_DQ, W_UQ, W_DKV, W_UKV,
                                                  W_QR, W_KR, W_O, wb);
  dim3 fgrid(T / 128, 64); // y<32: proj_kv (longer, first); y>=32: proj_q
  proj_fused<<<fgrid, 256, 0, stream>>>(xb, wb, qnw, knw, qb, kb, vtg);
  dim3 agrid(16, 32); // paired q-tiles, uniform work
  attn_mfma<<<agrid, 256, 0, stream>>>(qb, kb, vtg, wb, out);
}

// Round 17
// 128.296 us; speedup vs baseline: 1.1377x; 1.1377x over previous
//
#include <hip/hip_runtime.h>
#include <hip/hip_bf16.h>
#include <math.h>

namespace {

constexpr int T  = 2048;
constexpr int HD = 64;
constexpr float EPS = 1.1920929e-07f;
// SCALE * log2(e), folded into q at proj_q write time -> attn softmax runs in exp2 domain
constexpr float PS = 0.125f * 1.44269504f;

// bf16 weight pool offsets (in elements)
constexpr int OFF_DQ  = 0;       // 512*64
constexpr int OFF_UQ  = 32768;   // 64*512
constexpr int OFF_DKV = 65536;   // 1024*64
constexpr int OFF_UKV = 131072;  // 128*1024
constexpr int OFF_QR  = 262144;  // 64*64
constexpr int OFF_KR  = 266240;  // 64*64
constexpr int OFF_O   = 270336;  // 64*64
constexpr int W_TOTAL = 274432;

typedef __attribute__((ext_vector_type(8))) short bf8v;  // 8 bf16 (4 VGPR)
typedef __attribute__((ext_vector_type(4))) float f4v;   // MFMA C/D

#define MFMA16(a, b, c) __builtin_amdgcn_mfma_f32_16x16x32_bf16((a), (b), (c), 0, 0, 0)

// full-strength barrier for raw s_barrier use (rule #18 class): compiler
// memory fences both sides so gload_lds issues can't be hoisted across.
#define HARD_BARRIER()                                   \
  do {                                                   \
    asm volatile("" ::: "memory");                       \
    __builtin_amdgcn_s_barrier();                        \
    asm volatile("" ::: "memory");                       \
    __builtin_amdgcn_sched_barrier(0);                   \
  } while (0)

__device__ __forceinline__ short f2bf(float f) {
  union { float f; unsigned u; } v; v.f = f;
  unsigned r = v.u + 0x7FFFu + ((v.u >> 16) & 1u); // RNE
  return (short)(r >> 16);
}

__device__ __forceinline__ f4v z4() { f4v z = {0.f, 0.f, 0.f, 0.f}; return z; }

// XOR swizzles: spread row-strided b128 accesses across banks (m214 pattern)
__device__ __forceinline__ int swz128(int b) { return b ^ (((b >> 7) & 7) << 4); }
__device__ __forceinline__ int swz256(int b) { return b ^ (((b >> 8) & 7) << 4); }

__device__ __forceinline__ bf8v ldA128(const short* lds, int row, int k) {
  return *(const bf8v*)((const char*)lds + swz128(row * 128 + k * 2));
}
__device__ __forceinline__ bf8v ldA256(const short* lds, int row, int k) {
  return *(const bf8v*)((const char*)lds + swz256(row * 256 + k * 2));
}

// scatter a 16x16 D-fragment (col=lane&15, row=(lane>>4)*4+r) as bf16 into LDS
__device__ __forceinline__ void scat128(short* lds, int row0, int lane, int nt, f4v v) {
  int col = nt * 16 + (lane & 15);
  int r0 = row0 + ((lane >> 4) << 2);
#pragma unroll
  for (int r = 0; r < 4; ++r)
    *(short*)((char*)lds + swz128((r0 + r) * 128 + col * 2)) = f2bf(v[r]);
}
__device__ __forceinline__ void scat256(short* lds, int row0, int lane, int col, f4v v) {
  int r0 = row0 + ((lane >> 4) << 2);
#pragma unroll
  for (int r = 0; r < 4; ++r)
    *(short*)((char*)lds + swz256((r0 + r) * 256 + col * 2)) = f2bf(v[r]);
}

// async global->LDS, 16B per lane; LDS dest wave-uniform base + lane*16
__device__ __forceinline__ void gload_lds16(const void* g, void* l) {
  __builtin_amdgcn_global_load_lds(
      (const __attribute__((address_space(1))) void*)g,
      (__attribute__((address_space(3))) void*)l, 16, 0, 0);
}

// ---------------------------------------------------------------------------
// conversions
// ---------------------------------------------------------------------------
__global__ __launch_bounds__(256) void cvt_x_kernel(const float* __restrict__ x,
                                                    short* __restrict__ xb) {
  int i = (blockIdx.x * 256 + threadIdx.x) * 4; // over x linear (B,T,D)
  float4 v = *(const float4*)(x + i);
  int d = i & 1023, t = (i >> 10) & 2047, b = i >> 21;
  int h = d >> 6, dd = d & 63;
  short4 o;
  o.x = f2bf(v.x); o.y = f2bf(v.y); o.z = f2bf(v.z); o.w = f2bf(v.w);
  *(short4*)(xb + ((((size_t)b * 16 + h) * T + t) * 64 + dd)) = o;
}

__global__ __launch_bounds__(256) void cvt_w_kernel(
    const float* __restrict__ W_DQ, const float* __restrict__ W_UQ,
    const float* __restrict__ W_DKV, const float* __restrict__ W_UKV,
    const float* __restrict__ W_QR, const float* __restrict__ W_KR,
    const float* __restrict__ W_O, short* __restrict__ wb) {
  int i = blockIdx.x * 256 + threadIdx.x;
  const float* src; int off;
  if      (i < 32768)  { src = W_DQ;  off = 0; }
  else if (i < 65536)  { src = W_UQ;  off = 32768; }
  else if (i < 131072) { src = W_DKV; off = 65536; }
  else if (i < 262144) { src = W_UKV; off = 131072; }
  else if (i < 266240) { src = W_QR;  off = 262144; }
  else if (i < 270336) { src = W_KR;  off = 266240; }
  else                 { src = W_O;   off = 270336; }
  wb[i] = f2bf(src[i - off]);
}

// ---------------------------------------------------------------------------
// proj_q v2 (round-10 verbatim; __syncthreads-based, airtight)
// ---------------------------------------------------------------------------
__global__ __launch_bounds__(256) void proj_q_mfma(
    const short* __restrict__ xb, const short* __restrict__ wb,
    const float* __restrict__ qnw, short* __restrict__ qb) {
  __shared__ __attribute__((aligned(16))) short Xs[128 * 64];   // 16KB
  __shared__ __attribute__((aligned(16))) short Wd[2][64 * 64]; // 2x8KB
  __shared__ __attribute__((aligned(16))) short Wu[2][64 * 64]; // 2x8KB
  __shared__ __attribute__((aligned(16))) short Cs[128 * 64];   // 16KB

  const int tid = threadIdx.x, lane = tid & 63, w = tid >> 6;
  const int bh = blockIdx.y, t0 = blockIdx.x * 128;
  const int c16 = lane & 15;
  const int koff = (lane >> 4) << 3;

  auto stageWd = [&](int lc) {
    const char* src = (const char*)(wb + OFF_DQ + lc * 64 * 64);
    char* dst = (char*)&Wd[lc & 1][0];
#pragma unroll
    for (int p = 0; p < 2; ++p) {
      const int base = p * 256 + w * 64;
      gload_lds16(src + swz128((base + lane) * 16), dst + base * 16);
    }
  };
  auto stageWu = [&](int lc) {
    const char* src = (const char*)(wb + OFF_UQ + lc * 64);
    char* dst = (char*)&Wu[lc & 1][0];
#pragma unroll
    for (int p = 0; p < 2; ++p) {
      const int base = p * 256 + w * 64;
      const int lb = swz128((base + lane) * 16);
      gload_lds16(src + (size_t)(lb >> 7) * 1024 + (lb & 127), dst + base * 16);
    }
  };

  {
    const char* src = (const char*)(xb + ((size_t)bh * T + t0) * 64);
#pragma unroll
    for (int p = 0; p < 4; ++p) {
      const int base = p * 256 + w * 64;
      gload_lds16(src + swz128((base + lane) * 16), (char*)Xs + base * 16);
    }
  }
  stageWd(0);
  stageWu(0);
  __syncthreads();

  f4v acc[2][4];
#pragma unroll
  for (int rg = 0; rg < 2; ++rg)
#pragma unroll
    for (int nt = 0; nt < 4; ++nt) acc[rg][nt] = z4();

  for (int lc = 0; lc < 8; ++lc) {
    if (lc < 7) { stageWd(lc + 1); stageWu(lc + 1); }
    else {
      const char* src = (const char*)(wb + OFF_QR);
      char* dst = (char*)&Wd[0][0];
#pragma unroll
      for (int p = 0; p < 2; ++p) {
        const int base = p * 256 + w * 64;
        gload_lds16(src + swz128((base + lane) * 16), dst + base * 16);
      }
    }
    const short* Wdc = &Wd[lc & 1][0];
    const short* Wuc = &Wu[lc & 1][0];

    f4v cc[2][4];
#pragma unroll
    for (int rg = 0; rg < 2; ++rg)
#pragma unroll
      for (int nt = 0; nt < 4; ++nt) cc[rg][nt] = z4();
#pragma unroll
    for (int rg = 0; rg < 2; ++rg)
#pragma unroll
      for (int ks = 0; ks < 2; ++ks) {
        bf8v a = ldA128(Xs, w * 32 + rg * 16 + c16, ks * 32 + koff);
#pragma unroll
        for (int nt = 0; nt < 4; ++nt) {
          bf8v b = ldA128(Wdc, nt * 16 + c16, ks * 32 + koff);
          cc[rg][nt] = MFMA16(a, b, cc[rg][nt]);
        }
      }
#pragma unroll
    for (int rg = 0; rg < 2; ++rg)
#pragma unroll
      for (int nt = 0; nt < 4; ++nt) scat128(Cs, w * 32 + rg * 16, lane, nt, cc[rg][nt]);
#pragma unroll
    for (int rg = 0; rg < 2; ++rg)
#pragma unroll
      for (int ks = 0; ks < 2; ++ks) {
        bf8v a = ldA128(Cs, w * 32 + rg * 16 + c16, ks * 32 + koff);
#pragma unroll
        for (int nt = 0; nt < 4; ++nt) {
          bf8v b = ldA128(Wuc, nt * 16 + c16, ks * 32 + koff);
          acc[rg][nt] = MFMA16(a, b, acc[rg][nt]);
        }
      }
    __syncthreads();
  }

  float w4[4];
#pragma unroll
  for (int nt = 0; nt < 4; ++nt) w4[nt] = qnw[nt * 16 + c16] * PS;
#pragma unroll
  for (int rg = 0; rg < 2; ++rg)
#pragma unroll
    for (int r = 0; r < 4; ++r) {
      float ss = 0.f;
#pragma unroll
      for (int nt = 0; nt < 4; ++nt) ss += acc[rg][nt][r] * acc[rg][nt][r];
      ss += __shfl_xor(ss, 1, 16); ss += __shfl_xor(ss, 2, 16);
      ss += __shfl_xor(ss, 4, 16); ss += __shfl_xor(ss, 8, 16);
      float inv = rsqrtf(ss * (1.f / 64.f) + EPS);
#pragma unroll
      for (int nt = 0; nt < 4; ++nt) acc[rg][nt][r] *= inv * w4[nt];
    }

#pragma unroll
  for (int rg = 0; rg < 2; ++rg)
#pragma unroll
    for (int nt = 0; nt < 4; ++nt) scat128(Cs, w * 32 + rg * 16, lane, nt, acc[rg][nt]);

  f4v qr[2][4];
#pragma unroll
  for (int rg = 0; rg < 2; ++rg)
#pragma unroll
    for (int nt = 0; nt < 4; ++nt) qr[rg][nt] = z4();
#pragma unroll
  for (int rg = 0; rg < 2; ++rg)
#pragma unroll
    for (int ks = 0; ks < 2; ++ks) {
      bf8v a = ldA128(Cs, w * 32 + rg * 16 + c16, ks * 32 + koff);
#pragma unroll
      for (int nt = 0; nt < 4; ++nt) {
        bf8v b = ldA128(&Wd[0][0], nt * 16 + c16, ks * 32 + koff);
        qr[rg][nt] = MFMA16(a, b, qr[rg][nt]);
      }
    }
#pragma unroll
  for (int rg = 0; rg < 2; ++rg)
#pragma unroll
    for (int nt = 0; nt < 4; ++nt) scat128(Xs, w * 32 + rg * 16, lane, nt, qr[rg][nt]);
  __syncthreads();

  short* qdst = qb + ((size_t)bh * T + t0) * 128;
#pragma unroll
  for (int p = 0; p < 4; ++p) {
    int ci = tid + p * 256;
    int r = ci >> 3, c = (ci & 7) << 3;
    *(bf8v*)(qdst + (size_t)r * 128 + c) =
        *(const bf8v*)((const char*)Cs + swz128(ci * 16));
    *(bf8v*)(qdst + (size_t)r * 128 + 64 + c) =
        *(const bf8v*)((const char*)Xs + swz128(ci * 16));
  }
}

// ---------------------------------------------------------------------------
// proj_kv v2 (round-10 verbatim)
// ---------------------------------------------------------------------------
__global__ __launch_bounds__(256) void proj_kv_mfma(
    const short* __restrict__ xb, const short* __restrict__ wb,
    const float* __restrict__ knw, short* __restrict__ kb, short* __restrict__ vtg) {
  __shared__ __attribute__((aligned(16))) short Xs[128 * 64];    // 16KB
  __shared__ __attribute__((aligned(16))) short Wd[2][64 * 64];  // 2x8KB
  __shared__ __attribute__((aligned(16))) short Wu[2][128 * 64]; // 2x16KB (-> Ko 32KB)
  __shared__ __attribute__((aligned(16))) short Cs[128 * 64];    // 16KB (-> Vt)

  const int tid = threadIdx.x, lane = tid & 63, w = tid >> 6;
  const int bh = blockIdx.y, t0 = blockIdx.x * 128;
  const int c16 = lane & 15;
  const int g4 = lane >> 4;
  const int koff = g4 << 3;
  const int rg4 = g4 << 2;

  auto stageWd = [&](int lc) {
    const char* src = (const char*)(wb + OFF_DKV + lc * 64 * 64);
    char* dst = (char*)&Wd[lc & 1][0];
#pragma unroll
    for (int p = 0; p < 2; ++p) {
      const int base = p * 256 + w * 64;
      gload_lds16(src + swz128((base + lane) * 16), dst + base * 16);
    }
  };
  auto stageWu = [&](int lc) {
    const char* src = (const char*)(wb + OFF_UKV + lc * 64);
    char* dst = (char*)&Wu[lc & 1][0];
#pragma unroll
    for (int p = 0; p < 4; ++p) {
      const int base = p * 256 + w * 64;
      const int lb = swz128((base + lane) * 16);
      gload_lds16(src + (size_t)(lb >> 7) * 2048 + (lb & 127), dst + base * 16);
    }
  };

  {
    const char* src = (const char*)(xb + ((size_t)bh * T + t0) * 64);
#pragma unroll
    for (int p = 0; p < 4; ++p) {
      const int base = p * 256 + w * 64;
      gload_lds16(src + swz128((base + lane) * 16), (char*)Xs + base * 16);
    }
  }
  stageWd(0);
  stageWu(0);
  __syncthreads();

  f4v acc[2][8];
#pragma unroll
  for (int rg = 0; rg < 2; ++rg)
#pragma unroll
    for (int nt = 0; nt < 8; ++nt) acc[rg][nt] = z4();

  for (int lc = 0; lc < 16; ++lc) {
    if (lc < 15) { stageWd(lc + 1); stageWu(lc + 1); }
    else {
      const char* src = (const char*)(wb + OFF_KR);
      char* dst = (char*)&Wd[0][0];
#pragma unroll
      for (int p = 0; p < 2; ++p) {
        const int base = p * 256 + w * 64;
        gload_lds16(src + swz128((base + lane) * 16), dst + base * 16);
      }
    }
    const short* Wdc = &Wd[lc & 1][0];
    const short* Wuc = &Wu[lc & 1][0];

    f4v cc[2][4];
#pragma unroll
    for (int rg = 0; rg < 2; ++rg)
#pragma unroll
      for (int nt = 0; nt < 4; ++nt) cc[rg][nt] = z4();
#pragma unroll
    for (int rg = 0; rg < 2; ++rg)
#pragma unroll
      for (int ks = 0; ks < 2; ++ks) {
        bf8v a = ldA128(Xs, w * 32 + rg * 16 + c16, ks * 32 + koff);
#pragma unroll
        for (int nt = 0; nt < 4; ++nt) {
          bf8v b = ldA128(Wdc, nt * 16 + c16, ks * 32 + koff);
          cc[rg][nt] = MFMA16(a, b, cc[rg][nt]);
        }
      }
#pragma unroll
    for (int rg = 0; rg < 2; ++rg)
#pragma unroll
      for (int nt = 0; nt < 4; ++nt) scat128(Cs, w * 32 + rg * 16, lane, nt, cc[rg][nt]);
#pragma unroll
    for (int rg = 0; rg < 2; ++rg)
#pragma unroll
      for (int ks = 0; ks < 2; ++ks) {
        bf8v a = ldA128(Cs, w * 32 + rg * 16 + c16, ks * 32 + koff);
#pragma unroll
        for (int nt = 0; nt < 8; ++nt) {
          bf8v b = ldA128(Wuc, nt * 16 + c16, ks * 32 + koff);
          acc[rg][nt] = MFMA16(a, b, acc[rg][nt]);
        }
      }
    __syncthreads();
  }

  float w4[4];
#pragma unroll
  for (int nt = 0; nt < 4; ++nt) w4[nt] = knw[nt * 16 + c16];
#pragma unroll
  for (int rg = 0; rg < 2; ++rg)
#pragma unroll
    for (int r = 0; r < 4; ++r) {
      float ss = 0.f;
#pragma unroll
      for (int nt = 0; nt < 4; ++nt) ss += acc[rg][nt][r] * acc[rg][nt][r];
      ss += __shfl_xor(ss, 1, 16); ss += __shfl_xor(ss, 2, 16);
      ss += __shfl_xor(ss, 4, 16); ss += __shfl_xor(ss, 8, 16);
      float inv = rsqrtf(ss * (1.f / 64.f) + EPS);
#pragma unroll
      for (int nt = 0; nt < 4; ++nt) acc[rg][nt][r] *= inv * w4[nt];
    }

  short* Ko = &Wu[0][0];
#pragma unroll
  for (int rg = 0; rg < 2; ++rg)
#pragma unroll
    for (int nt = 0; nt < 4; ++nt)
      scat256(Ko, w * 32 + rg * 16, lane, nt * 16 + c16, acc[rg][nt]);

#pragma unroll
  for (int rg = 0; rg < 2; ++rg)
#pragma unroll
    for (int nt = 0; nt < 4; ++nt) {
      const int d = nt * 16 + c16;
      const int tc0 = w * 32 + rg * 16 + rg4;
#pragma unroll
      for (int r = 0; r < 4; ++r)
        *(short*)((char*)Cs + swz256(d * 256 + (tc0 + r) * 2)) =
            f2bf(acc[rg][4 + nt][r]);
    }

  f4v kr[2][4];
#pragma unroll
  for (int rg = 0; rg < 2; ++rg)
#pragma unroll
    for (int nt = 0; nt < 4; ++nt) kr[rg][nt] = z4();
#pragma unroll
  for (int rg = 0; rg < 2; ++rg)
#pragma unroll
    for (int ks = 0; ks < 2; ++ks) {
      bf8v a = ldA128(Xs, w * 32 + rg * 16 + c16, ks * 32 + koff);
#pragma unroll
      for (int nt = 0; nt < 4; ++nt) {
        bf8v b = ldA128(&Wd[0][0], nt * 16 + c16, ks * 32 + koff);
        kr[rg][nt] = MFMA16(a, b, kr[rg][nt]);
      }
    }
#pragma unroll
  for (int rg = 0; rg < 2; ++rg)
#pragma unroll
    for (int nt = 0; nt < 4; ++nt)
      scat256(Ko, w * 32 + rg * 16, lane, 64 + nt * 16 + c16, kr[rg][nt]);
  __syncthreads();

  short* kdst = kb + ((size_t)bh * T + t0) * 128;
#pragma unroll
  for (int p = 0; p < 8; ++p) {
    int ci = tid + p * 256;
    int r = ci >> 4, c = (ci & 15) << 3;
    *(bf8v*)(kdst + (size_t)r * 128 + c) =
        *(const bf8v*)((const char*)Ko + swz256(ci * 16));
  }
#pragma unroll
  for (int p = 0; p < 4; ++p) {
    int ci = tid + p * 256;
    int d = ci >> 4, c = (ci & 15) << 3;
    *(bf8v*)(vtg + ((size_t)bh * 64 + d) * T + t0 + c) =
        *(const bf8v*)((const char*)Cs + swz256(ci * 16));
  }
}

// ---------------------------------------------------------------------------
// attn v7d: v7c + (1) Vs[3] -> end-of-tile barrier REMOVED (pre-PV barrier
// already guarantees QK(gg) done before Ks[gg%3] overwrite; 3 V bufs put
// stageV(gg+1) two buffers away from any reader) and (2) s_setprio(1)
// around MFMA clusters (T5; phase-split structure). One barrier per tile.
// ---------------------------------------------------------------------------
__global__ __launch_bounds__(256) void attn_mfma(
    const short* __restrict__ qb, const short* __restrict__ kb,
    const short* __restrict__ vtg, const short* __restrict__ wb,
    float* __restrict__ out) {
  __shared__ __attribute__((aligned(16))) short Ks[3][64 * 128]; // swz256, 16KB ea
  __shared__ __attribute__((aligned(16))) short Vs[3][64 * 64];  // swz128, 8KB ea
  __shared__ __attribute__((aligned(16))) short Ps[64 * 64];     // swz128, 8KB

  const int tid = threadIdx.x, lane = tid & 63, w = tid >> 6;
  const int lin = blockIdx.y * 16 + blockIdx.x; // [0,512)
  const int xcd = lin & 7, slot = lin >> 3;     // slot [0,64)
  const int bh = xcd + 8 * (slot >> 4);         // 4 bh per XCD -> KV L2-resident
  const int px = slot & 15;
  const int qtA = px, qtB = 31 - px;
  const int cntA = qtA + 1;
  const int NT = 33;

  const int b = bh >> 4, h = bh & 15;
  const int c16 = lane & 15;
  const int g4 = lane >> 4;
  const int koff = g4 << 3;
  const int rg4 = g4 << 2;
  const int lbase = lane & 48;

  const short* kbh = kb + (size_t)bh * T * 128;
  const short* vbh = vtg + (size_t)bh * 64 * T;

  bf8v aqA[4], aqB[4], bwo[2][4];
  {
    const short* qA = qb + ((size_t)bh * T + qtA * 64 + w * 16 + c16) * 128;
    const short* qB = qb + ((size_t)bh * T + qtB * 64 + w * 16 + c16) * 128;
#pragma unroll
    for (int ks = 0; ks < 4; ++ks) {
      aqA[ks] = *(const bf8v*)(qA + ks * 32 + koff);
      aqB[ks] = *(const bf8v*)(qB + ks * 32 + koff);
    }
#pragma unroll
    for (int ks = 0; ks < 2; ++ks)
#pragma unroll
      for (int nt = 0; nt < 4; ++nt)
        bwo[ks][nt] = *(const bf8v*)(wb + OFF_O + (size_t)(nt * 16 + c16) * 64 +
                                     ks * 32 + koff);
  }

  auto ktile = [&](int gg) { return (gg < NT) ? ((gg < cntA) ? gg : gg - cntA) : 0; };

  auto stageK = [&](int gg) { // 4 gload_lds per wave
    const int jt = ktile(gg);
    const char* src = (const char*)(kbh + jt * 64 * 128);
    char* dst = (char*)&Ks[gg % 3][0];
#pragma unroll
    for (int p = 0; p < 4; ++p) {
      const int base = p * 256 + w * 64;
      gload_lds16(src + swz256((base + lane) * 16), dst + base * 16);
    }
  };
  auto stageV = [&](int gg) { // 2 gload_lds per wave
    const int jt = ktile(gg);
    char* dst = (char*)&Vs[gg % 3][0];
#pragma unroll
    for (int p = 0; p < 2; ++p) {
      const int base = p * 256 + w * 64;
      const int tb = swz128((base + lane) * 16);
      const int r = tb >> 7, cb = tb & 127;
      gload_lds16((const char*)vbh + ((size_t)r * T + jt * 64) * 2 + cb,
                  dst + base * 16);
    }
  };

  stageK(0);
  stageK(1);
  stageV(0);
  asm volatile("s_waitcnt vmcnt(6)" ::: "memory");
  HARD_BARRIER();

  int gg = 0;
  float* obase = out + (size_t)b * T * 1024 + h * 64;

  auto run_seg = [&](const int qt, const bf8v(&aq)[4]) {
    const int t0 = qt * 64;
    const int lrow = w * 16 + rg4;
    const int qglob = t0 + w * 16 + c16;

    f4v ctx[4];
    float m = -INFINITY, l = 0.f;
#pragma unroll
    for (int nt = 0; nt < 4; ++nt) ctx[nt] = z4();

    for (int jt = 0; jt <= qt; ++jt, ++gg) {
      const short* Kb = &Ks[gg % 3][0];
      const short* Vb = &Vs[gg % 3][0];
      stageK(gg + 2);
      stageV(gg + 1);

      const int j0 = jt * 64;
      const bool diag = (jt == qt);

      f4v s[4];
#pragma unroll
      for (int nt = 0; nt < 4; ++nt) s[nt] = z4();
      __builtin_amdgcn_s_setprio(1);
#pragma unroll
      for (int ks = 0; ks < 4; ++ks) {
#pragma unroll
        for (int nt = 0; nt < 4; ++nt) {
          bf8v bk = ldA256(Kb, nt * 16 + c16, ks * 32 + koff);
          s[nt] = MFMA16(bk, aq[ks], s[nt]); // A=K, B=Q (swapped)
        }
      }
      __builtin_amdgcn_s_setprio(0);

      if (diag) {
#pragma unroll
        for (int nt = 0; nt < 4; ++nt)
#pragma unroll
          for (int r = 0; r < 4; ++r)
            if (j0 + nt * 16 + rg4 + r > qglob) s[nt][r] = -INFINITY;
      }

      f4v mnt;
#pragma unroll
      for (int r = 0; r < 4; ++r)
        mnt[r] = fmaxf(fmaxf(s[0][r], s[1][r]), fmaxf(s[2][r], s[3][r]));
      float mx = fmaxf(fmaxf(mnt[0], mnt[1]), fmaxf(mnt[2], mnt[3]));
      mx = fmaxf(mx, __shfl_xor(mx, 16));
      mx = fmaxf(mx, __shfl_xor(mx, 32));

      if (__any(mx - m > 8.f)) {
        const float mn  = fmaxf(m, mx);
        const float scl = __builtin_amdgcn_exp2f(m - mn);
        l *= scl; m = mn;
        float sr[4];
#pragma unroll
        for (int r = 0; r < 4; ++r) sr[r] = __shfl(scl, lbase + rg4 + r);
#pragma unroll
        for (int nt = 0; nt < 4; ++nt)
#pragma unroll
          for (int r = 0; r < 4; ++r) ctx[nt][r] *= sr[r];
      }

#pragma unroll
      for (int nt = 0; nt < 4; ++nt)
#pragma unroll
        for (int r = 0; r < 4; ++r)
          s[nt][r] = __builtin_amdgcn_exp2f(s[nt][r] - m);
      f4v sv = s[0] + s[1] + s[2] + s[3];
      float rs = (sv[0] + sv[1]) + (sv[2] + sv[3]);
      rs += __shfl_xor(rs, 16);
      rs += __shfl_xor(rs, 32);
      l += rs;

      {
        char* prow = (char*)Ps;
        const int rbase = (w * 16 + c16) * 128 + koff;
#pragma unroll
        for (int nt = 0; nt < 4; ++nt) {
          __hip_bfloat162 h0 = __float22bfloat162_rn(make_float2(s[nt][0], s[nt][1]));
          __hip_bfloat162 h1 = __float22bfloat162_rn(make_float2(s[nt][2], s[nt][3]));
          uint2 d;
          d.x = *(unsigned int*)&h0;
          d.y = *(unsigned int*)&h1;
          *(uint2*)(prow + swz128(rbase + nt * 32)) = d;
        }
      }

      // drain prev tile's loads (leaves this tile's 6 in flight), then barrier
      // so ALL waves' V(gg) chunks are landed before any PV read. This is the
      // ONLY barrier per tile: Ks[gg%3] overwrite (stageK(gg+3) at iter gg+1)
      // is safe because all QK(gg) completed here; Vs[(gg+1)%3] staged now is
      // 2 buffers from Vs[(gg-2)%3]'s readers, all long past.
      asm volatile("s_waitcnt vmcnt(6)" ::: "memory");
      HARD_BARRIER();

      __builtin_amdgcn_s_setprio(1);
#pragma unroll
      for (int ks = 0; ks < 2; ++ks) {
        bf8v pa = ldA128(Ps, w * 16 + c16, ks * 32 + koff);
#pragma unroll
        for (int nt = 0; nt < 4; ++nt) {
          bf8v vf = ldA128(Vb, nt * 16 + c16, ks * 32 + koff);
          ctx[nt] = MFMA16(pa, vf, ctx[nt]);
        }
      }
      __builtin_amdgcn_s_setprio(0);
    }

    float linv[4];
#pragma unroll
    for (int r = 0; r < 4; ++r) linv[r] = 1.0f / __shfl(l, lbase + rg4 + r);
    f4v cn[4];
#pragma unroll
    for (int nt = 0; nt < 4; ++nt)
#pragma unroll
      for (int r = 0; r < 4; ++r) cn[nt][r] = ctx[nt][r] * linv[r];
#pragma unroll
    for (int nt = 0; nt < 4; ++nt) scat128(Ps, w * 16, lane, nt, cn[nt]);

    f4v o[4];
#pragma unroll
    for (int nt = 0; nt < 4; ++nt) o[nt] = z4();
#pragma unroll
    for (int ks = 0; ks < 2; ++ks) {
      bf8v pa = ldA128(Ps, w * 16 + c16, ks * 32 + koff);
#pragma unroll
      for (int nt = 0; nt < 4; ++nt) o[nt] = MFMA16(pa, bwo[ks][nt], o[nt]);
    }

#pragma unroll
    for (int nt = 0; nt < 4; ++nt) {
#pragma unroll
      for (int r = 0; r < 4; ++r)
        obase[(size_t)(t0 + lrow + r) * 1024 + nt * 16 + c16] = o[nt][r];
    }
  };

  run_seg(qtA, aqA);
  run_seg(qtB, aqB);
}

} // namespace

extern "C" void kernel_launch(void* const* d_in, const int* in_sizes, int n_in,
                              void* d_out, int out_size, void* d_ws, size_t ws_size,
                              hipStream_t stream) {
  (void)in_sizes; (void)n_in; (void)out_size; (void)ws_size;
  const float* x     = (const float*)d_in[0];
  const float* W_DQ  = (const float*)d_in[1];
  const float* W_UQ  = (const float*)d_in[2];
  const float* W_DKV = (const float*)d_in[3];
  const float* W_UKV = (const float*)d_in[4];
  const float* W_QR  = (const float*)d_in[5];
  const float* W_KR  = (const float*)d_in[6];
  const float* W_O   = (const float*)d_in[7];
  const float* qnw   = (const float*)d_in[8];
  const float* knw   = (const float*)d_in[9];
  float* out = (float*)d_out;

  short* ws = (short*)d_ws;
  short* xb  = ws;                          // 4,194,304
  short* qb  = ws + (size_t)4194304;        // 8,388,608
  short* kb  = ws + (size_t)12582912;       // 8,388,608
  short* vtg = ws + (size_t)20971520;       // 4,194,304
  short* wb  = ws + (size_t)25165824;       // 274,432

  cvt_x_kernel<<<4096, 256, 0, stream>>>(x, xb);
  cvt_w_kernel<<<W_TOTAL / 256, 256, 0, stream>>>(W_DQ, W_UQ, W_DKV, W_UKV,
                                                  W_QR, W_KR, W_O, wb);
  dim3 pgrid(T / 128, 32); // 128-row tiles
  proj_q_mfma<<<pgrid, 256, 0, stream>>>(xb, wb, qnw, qb);
  proj_kv_mfma<<<pgrid, 256, 0, stream>>>(xb, wb, knw, kb, vtg);
  dim3 agrid(16, 32); // paired q-tiles, uniform work
  attn_mfma<<<agrid, 256, 0, stream>>>(qb, kb, vtg, wb, out);
}

// Round 18
// 127.701 us; speedup vs baseline: 1.1430x; 1.0047x over previous
//
#include <hip/hip_runtime.h>
#include <hip/hip_bf16.h>
#include <math.h>

namespace {

constexpr int T  = 2048;
constexpr int HD = 64;
constexpr float EPS = 1.1920929e-07f;
// SCALE * log2(e), folded into q at proj_q write time -> attn softmax runs in exp2 domain
constexpr float PS = 0.125f * 1.44269504f;

// bf16 weight pool offsets (in elements)
constexpr int OFF_DQ  = 0;       // 512*64
constexpr int OFF_UQ  = 32768;   // 64*512
constexpr int OFF_DKV = 65536;   // 1024*64
constexpr int OFF_UKV = 131072;  // 128*1024
constexpr int OFF_QR  = 262144;  // 64*64
constexpr int OFF_KR  = 266240;  // 64*64
constexpr int OFF_O   = 270336;  // 64*64
constexpr int W_TOTAL = 274432;

typedef __attribute__((ext_vector_type(8))) short bf8v;  // 8 bf16 (4 VGPR)
typedef __attribute__((ext_vector_type(4))) float f4v;   // MFMA C/D

#define MFMA16(a, b, c) __builtin_amdgcn_mfma_f32_16x16x32_bf16((a), (b), (c), 0, 0, 0)

// full-strength barrier for raw s_barrier use (rule #18 class): compiler
// memory fences both sides so gload_lds issues can't be hoisted across.
#define HARD_BARRIER()                                   \
  do {                                                   \
    asm volatile("" ::: "memory");                       \
    __builtin_amdgcn_s_barrier();                        \
    asm volatile("" ::: "memory");                       \
    __builtin_amdgcn_sched_barrier(0);                   \
  } while (0)

__device__ __forceinline__ short f2bf(float f) {
  union { float f; unsigned u; } v; v.f = f;
  unsigned r = v.u + 0x7FFFu + ((v.u >> 16) & 1u); // RNE
  return (short)(r >> 16);
}

__device__ __forceinline__ f4v z4() { f4v z = {0.f, 0.f, 0.f, 0.f}; return z; }

// XOR swizzles: spread row-strided b128 accesses across banks (m214 pattern)
__device__ __forceinline__ int swz128(int b) { return b ^ (((b >> 7) & 7) << 4); }
__device__ __forceinline__ int swz256(int b) { return b ^ (((b >> 8) & 7) << 4); }

__device__ __forceinline__ bf8v ldA128(const short* lds, int row, int k) {
  return *(const bf8v*)((const char*)lds + swz128(row * 128 + k * 2));
}
__device__ __forceinline__ bf8v ldA256(const short* lds, int row, int k) {
  return *(const bf8v*)((const char*)lds + swz256(row * 256 + k * 2));
}

// scatter a 16x16 D-fragment (col=lane&15, row=(lane>>4)*4+r) as bf16 into LDS
__device__ __forceinline__ void scat128(short* lds, int row0, int lane, int nt, f4v v) {
  int col = nt * 16 + (lane & 15);
  int r0 = row0 + ((lane >> 4) << 2);
#pragma unroll
  for (int r = 0; r < 4; ++r)
    *(short*)((char*)lds + swz128((r0 + r) * 128 + col * 2)) = f2bf(v[r]);
}
__device__ __forceinline__ void scat256(short* lds, int row0, int lane, int col, f4v v) {
  int r0 = row0 + ((lane >> 4) << 2);
#pragma unroll
  for (int r = 0; r < 4; ++r)
    *(short*)((char*)lds + swz256((r0 + r) * 256 + col * 2)) = f2bf(v[r]);
}

// async global->LDS, 16B per lane; LDS dest wave-uniform base + lane*16
__device__ __forceinline__ void gload_lds16(const void* g, void* l) {
  __builtin_amdgcn_global_load_lds(
      (const __attribute__((address_space(1))) void*)g,
      (__attribute__((address_space(3))) void*)l, 16, 0, 0);
}

// ---------------------------------------------------------------------------
// combined conversion: blocks [0,4096) convert x; [4096, 4096+1072) convert W
// ---------------------------------------------------------------------------
__global__ __launch_bounds__(256) void cvt_all_kernel(
    const float* __restrict__ x, const float* __restrict__ W_DQ,
    const float* __restrict__ W_UQ, const float* __restrict__ W_DKV,
    const float* __restrict__ W_UKV, const float* __restrict__ W_QR,
    const float* __restrict__ W_KR, const float* __restrict__ W_O,
    short* __restrict__ xb, short* __restrict__ wb) {
  if (blockIdx.x < 4096) {
    int i = (blockIdx.x * 256 + threadIdx.x) * 4; // over x linear (B,T,D)
    float4 v = *(const float4*)(x + i);
    int d = i & 1023, t = (i >> 10) & 2047, b = i >> 21;
    int h = d >> 6, dd = d & 63;
    short4 o;
    o.x = f2bf(v.x); o.y = f2bf(v.y); o.z = f2bf(v.z); o.w = f2bf(v.w);
    *(short4*)(xb + ((((size_t)b * 16 + h) * T + t) * 64 + dd)) = o;
  } else {
    int i = (blockIdx.x - 4096) * 256 + threadIdx.x;
    const float* src; int off;
    if      (i < 32768)  { src = W_DQ;  off = 0; }
    else if (i < 65536)  { src = W_UQ;  off = 32768; }
    else if (i < 131072) { src = W_DKV; off = 65536; }
    else if (i < 262144) { src = W_UKV; off = 131072; }
    else if (i < 266240) { src = W_QR;  off = 262144; }
    else if (i < 270336) { src = W_KR;  off = 266240; }
    else                 { src = W_O;   off = 270336; }
    wb[i] = f2bf(src[i - off]);
  }
}

// ---------------------------------------------------------------------------
// proj_q v2 (round-10 verbatim; __syncthreads-based, airtight)
// ---------------------------------------------------------------------------
__global__ __launch_bounds__(256) void proj_q_mfma(
    const short* __restrict__ xb, const short* __restrict__ wb,
    const float* __restrict__ qnw, short* __restrict__ qb) {
  __shared__ __attribute__((aligned(16))) short Xs[128 * 64];   // 16KB
  __shared__ __attribute__((aligned(16))) short Wd[2][64 * 64]; // 2x8KB
  __shared__ __attribute__((aligned(16))) short Wu[2][64 * 64]; // 2x8KB
  __shared__ __attribute__((aligned(16))) short Cs[128 * 64];   // 16KB

  const int tid = threadIdx.x, lane = tid & 63, w = tid >> 6;
  const int bh = blockIdx.y, t0 = blockIdx.x * 128;
  const int c16 = lane & 15;
  const int koff = (lane >> 4) << 3;

  auto stageWd = [&](int lc) {
    const char* src = (const char*)(wb + OFF_DQ + lc * 64 * 64);
    char* dst = (char*)&Wd[lc & 1][0];
#pragma unroll
    for (int p = 0; p < 2; ++p) {
      const int base = p * 256 + w * 64;
      gload_lds16(src + swz128((base + lane) * 16), dst + base * 16);
    }
  };
  auto stageWu = [&](int lc) {
    const char* src = (const char*)(wb + OFF_UQ + lc * 64);
    char* dst = (char*)&Wu[lc & 1][0];
#pragma unroll
    for (int p = 0; p < 2; ++p) {
      const int base = p * 256 + w * 64;
      const int lb = swz128((base + lane) * 16);
      gload_lds16(src + (size_t)(lb >> 7) * 1024 + (lb & 127), dst + base * 16);
    }
  };

  {
    const char* src = (const char*)(xb + ((size_t)bh * T + t0) * 64);
#pragma unroll
    for (int p = 0; p < 4; ++p) {
      const int base = p * 256 + w * 64;
      gload_lds16(src + swz128((base + lane) * 16), (char*)Xs + base * 16);
    }
  }
  stageWd(0);
  stageWu(0);
  __syncthreads();

  f4v acc[2][4];
#pragma unroll
  for (int rg = 0; rg < 2; ++rg)
#pragma unroll
    for (int nt = 0; nt < 4; ++nt) acc[rg][nt] = z4();

  for (int lc = 0; lc < 8; ++lc) {
    if (lc < 7) { stageWd(lc + 1); stageWu(lc + 1); }
    else {
      const char* src = (const char*)(wb + OFF_QR);
      char* dst = (char*)&Wd[0][0];
#pragma unroll
      for (int p = 0; p < 2; ++p) {
        const int base = p * 256 + w * 64;
        gload_lds16(src + swz128((base + lane) * 16), dst + base * 16);
      }
    }
    const short* Wdc = &Wd[lc & 1][0];
    const short* Wuc = &Wu[lc & 1][0];

    f4v cc[2][4];
#pragma unroll
    for (int rg = 0; rg < 2; ++rg)
#pragma unroll
      for (int nt = 0; nt < 4; ++nt) cc[rg][nt] = z4();
#pragma unroll
    for (int rg = 0; rg < 2; ++rg)
#pragma unroll
      for (int ks = 0; ks < 2; ++ks) {
        bf8v a = ldA128(Xs, w * 32 + rg * 16 + c16, ks * 32 + koff);
#pragma unroll
        for (int nt = 0; nt < 4; ++nt) {
          bf8v b = ldA128(Wdc, nt * 16 + c16, ks * 32 + koff);
          cc[rg][nt] = MFMA16(a, b, cc[rg][nt]);
        }
      }
#pragma unroll
    for (int rg = 0; rg < 2; ++rg)
#pragma unroll
      for (int nt = 0; nt < 4; ++nt) scat128(Cs, w * 32 + rg * 16, lane, nt, cc[rg][nt]);
#pragma unroll
    for (int rg = 0; rg < 2; ++rg)
#pragma unroll
      for (int ks = 0; ks < 2; ++ks) {
        bf8v a = ldA128(Cs, w * 32 + rg * 16 + c16, ks * 32 + koff);
#pragma unroll
        for (int nt = 0; nt < 4; ++nt) {
          bf8v b = ldA128(Wuc, nt * 16 + c16, ks * 32 + koff);
          acc[rg][nt] = MFMA16(a, b, acc[rg][nt]);
        }
      }
    __syncthreads();
  }

  float w4[4];
#pragma unroll
  for (int nt = 0; nt < 4; ++nt) w4[nt] = qnw[nt * 16 + c16] * PS;
#pragma unroll
  for (int rg = 0; rg < 2; ++rg)
#pragma unroll
    for (int r = 0; r < 4; ++r) {
      float ss = 0.f;
#pragma unroll
      for (int nt = 0; nt < 4; ++nt) ss += acc[rg][nt][r] * acc[rg][nt][r];
      ss += __shfl_xor(ss, 1, 16); ss += __shfl_xor(ss, 2, 16);
      ss += __shfl_xor(ss, 4, 16); ss += __shfl_xor(ss, 8, 16);
      float inv = rsqrtf(ss * (1.f / 64.f) + EPS);
#pragma unroll
      for (int nt = 0; nt < 4; ++nt) acc[rg][nt][r] *= inv * w4[nt];
    }

#pragma unroll
  for (int rg = 0; rg < 2; ++rg)
#pragma unroll
    for (int nt = 0; nt < 4; ++nt) scat128(Cs, w * 32 + rg * 16, lane, nt, acc[rg][nt]);

  f4v qr[2][4];
#pragma unroll
  for (int rg = 0; rg < 2; ++rg)
#pragma unroll
    for (int nt = 0; nt < 4; ++nt) qr[rg][nt] = z4();
#pragma unroll
  for (int rg = 0; rg < 2; ++rg)
#pragma unroll
    for (int ks = 0; ks < 2; ++ks) {
      bf8v a = ldA128(Cs, w * 32 + rg * 16 + c16, ks * 32 + koff);
#pragma unroll
      for (int nt = 0; nt < 4; ++nt) {
        bf8v b = ldA128(&Wd[0][0], nt * 16 + c16, ks * 32 + koff);
        qr[rg][nt] = MFMA16(a, b, qr[rg][nt]);
      }
    }
#pragma unroll
  for (int rg = 0; rg < 2; ++rg)
#pragma unroll
    for (int nt = 0; nt < 4; ++nt) scat128(Xs, w * 32 + rg * 16, lane, nt, qr[rg][nt]);
  __syncthreads();

  short* qdst = qb + ((size_t)bh * T + t0) * 128;
#pragma unroll
  for (int p = 0; p < 4; ++p) {
    int ci = tid + p * 256;
    int r = ci >> 3, c = (ci & 7) << 3;
    *(bf8v*)(qdst + (size_t)r * 128 + c) =
        *(const bf8v*)((const char*)Cs + swz128(ci * 16));
    *(bf8v*)(qdst + (size_t)r * 128 + 64 + c) =
        *(const bf8v*)((const char*)Xs + swz128(ci * 16));
  }
}

// ---------------------------------------------------------------------------
// proj_kv v2 (round-10 verbatim)
// ---------------------------------------------------------------------------
__global__ __launch_bounds__(256) void proj_kv_mfma(
    const short* __restrict__ xb, const short* __restrict__ wb,
    const float* __restrict__ knw, short* __restrict__ kb, short* __restrict__ vtg) {
  __shared__ __attribute__((aligned(16))) short Xs[128 * 64];    // 16KB
  __shared__ __attribute__((aligned(16))) short Wd[2][64 * 64];  // 2x8KB
  __shared__ __attribute__((aligned(16))) short Wu[2][128 * 64]; // 2x16KB (-> Ko 32KB)
  __shared__ __attribute__((aligned(16))) short Cs[128 * 64];    // 16KB (-> Vt)

  const int tid = threadIdx.x, lane = tid & 63, w = tid >> 6;
  const int bh = blockIdx.y, t0 = blockIdx.x * 128;
  const int c16 = lane & 15;
  const int g4 = lane >> 4;
  const int koff = g4 << 3;
  const int rg4 = g4 << 2;

  auto stageWd = [&](int lc) {
    const char* src = (const char*)(wb + OFF_DKV + lc * 64 * 64);
    char* dst = (char*)&Wd[lc & 1][0];
#pragma unroll
    for (int p = 0; p < 2; ++p) {
      const int base = p * 256 + w * 64;
      gload_lds16(src + swz128((base + lane) * 16), dst + base * 16);
    }
  };
  auto stageWu = [&](int lc) {
    const char* src = (const char*)(wb + OFF_UKV + lc * 64);
    char* dst = (char*)&Wu[lc & 1][0];
#pragma unroll
    for (int p = 0; p < 4; ++p) {
      const int base = p * 256 + w * 64;
      const int lb = swz128((base + lane) * 16);
      gload_lds16(src + (size_t)(lb >> 7) * 2048 + (lb & 127), dst + base * 16);
    }
  };

  {
    const char* src = (const char*)(xb + ((size_t)bh * T + t0) * 64);
#pragma unroll
    for (int p = 0; p < 4; ++p) {
      const int base = p * 256 + w * 64;
      gload_lds16(src + swz128((base + lane) * 16), (char*)Xs + base * 16);
    }
  }
  stageWd(0);
  stageWu(0);
  __syncthreads();

  f4v acc[2][8];
#pragma unroll
  for (int rg = 0; rg < 2; ++rg)
#pragma unroll
    for (int nt = 0; nt < 8; ++nt) acc[rg][nt] = z4();

  for (int lc = 0; lc < 16; ++lc) {
    if (lc < 15) { stageWd(lc + 1); stageWu(lc + 1); }
    else {
      const char* src = (const char*)(wb + OFF_KR);
      char* dst = (char*)&Wd[0][0];
#pragma unroll
      for (int p = 0; p < 2; ++p) {
        const int base = p * 256 + w * 64;
        gload_lds16(src + swz128((base + lane) * 16), dst + base * 16);
      }
    }
    const short* Wdc = &Wd[lc & 1][0];
    const short* Wuc = &Wu[lc & 1][0];

    f4v cc[2][4];
#pragma unroll
    for (int rg = 0; rg < 2; ++rg)
#pragma unroll
      for (int nt = 0; nt < 4; ++nt) cc[rg][nt] = z4();
#pragma unroll
    for (int rg = 0; rg < 2; ++rg)
#pragma unroll
      for (int ks = 0; ks < 2; ++ks) {
        bf8v a = ldA128(Xs, w * 32 + rg * 16 + c16, ks * 32 + koff);
#pragma unroll
        for (int nt = 0; nt < 4; ++nt) {
          bf8v b = ldA128(Wdc, nt * 16 + c16, ks * 32 + koff);
          cc[rg][nt] = MFMA16(a, b, cc[rg][nt]);
        }
      }
#pragma unroll
    for (int rg = 0; rg < 2; ++rg)
#pragma unroll
      for (int nt = 0; nt < 4; ++nt) scat128(Cs, w * 32 + rg * 16, lane, nt, cc[rg][nt]);
#pragma unroll
    for (int rg = 0; rg < 2; ++rg)
#pragma unroll
      for (int ks = 0; ks < 2; ++ks) {
        bf8v a = ldA128(Cs, w * 32 + rg * 16 + c16, ks * 32 + koff);
#pragma unroll
        for (int nt = 0; nt < 8; ++nt) {
          bf8v b = ldA128(Wuc, nt * 16 + c16, ks * 32 + koff);
          acc[rg][nt] = MFMA16(a, b, acc[rg][nt]);
        }
      }
    __syncthreads();
  }

  float w4[4];
#pragma unroll
  for (int nt = 0; nt < 4; ++nt) w4[nt] = knw[nt * 16 + c16];
#pragma unroll
  for (int rg = 0; rg < 2; ++rg)
#pragma unroll
    for (int r = 0; r < 4; ++r) {
      float ss = 0.f;
#pragma unroll
      for (int nt = 0; nt < 4; ++nt) ss += acc[rg][nt][r] * acc[rg][nt][r];
      ss += __shfl_xor(ss, 1, 16); ss += __shfl_xor(ss, 2, 16);
      ss += __shfl_xor(ss, 4, 16); ss += __shfl_xor(ss, 8, 16);
      float inv = rsqrtf(ss * (1.f / 64.f) + EPS);
#pragma unroll
      for (int nt = 0; nt < 4; ++nt) acc[rg][nt][r] *= inv * w4[nt];
    }

  short* Ko = &Wu[0][0];
#pragma unroll
  for (int rg = 0; rg < 2; ++rg)
#pragma unroll
    for (int nt = 0; nt < 4; ++nt)
      scat256(Ko, w * 32 + rg * 16, lane, nt * 16 + c16, acc[rg][nt]);

#pragma unroll
  for (int rg = 0; rg < 2; ++rg)
#pragma unroll
    for (int nt = 0; nt < 4; ++nt) {
      const int d = nt * 16 + c16;
      const int tc0 = w * 32 + rg * 16 + rg4;
#pragma unroll
      for (int r = 0; r < 4; ++r)
        *(short*)((char*)Cs + swz256(d * 256 + (tc0 + r) * 2)) =
            f2bf(acc[rg][4 + nt][r]);
    }

  f4v kr[2][4];
#pragma unroll
  for (int rg = 0; rg < 2; ++rg)
#pragma unroll
    for (int nt = 0; nt < 4; ++nt) kr[rg][nt] = z4();
#pragma unroll
  for (int rg = 0; rg < 2; ++rg)
#pragma unroll
    for (int ks = 0; ks < 2; ++ks) {
      bf8v a = ldA128(Xs, w * 32 + rg * 16 + c16, ks * 32 + koff);
#pragma unroll
      for (int nt = 0; nt < 4; ++nt) {
        bf8v b = ldA128(&Wd[0][0], nt * 16 + c16, ks * 32 + koff);
        kr[rg][nt] = MFMA16(a, b, kr[rg][nt]);
      }
    }
#pragma unroll
  for (int rg = 0; rg < 2; ++rg)
#pragma unroll
    for (int nt = 0; nt < 4; ++nt)
      scat256(Ko, w * 32 + rg * 16, lane, 64 + nt * 16 + c16, kr[rg][nt]);
  __syncthreads();

  short* kdst = kb + ((size_t)bh * T + t0) * 128;
#pragma unroll
  for (int p = 0; p < 8; ++p) {
    int ci = tid + p * 256;
    int r = ci >> 4, c = (ci & 15) << 3;
    *(bf8v*)(kdst + (size_t)r * 128 + c) =
        *(const bf8v*)((const char*)Ko + swz256(ci * 16));
  }
#pragma unroll
  for (int p = 0; p < 4; ++p) {
    int ci = tid + p * 256;
    int d = ci >> 4, c = (ci & 15) << 3;
    *(bf8v*)(vtg + ((size_t)bh * 64 + d) * T + t0 + c) =
        *(const bf8v*)((const char*)Cs + swz256(ci * 16));
  }
}

// ---------------------------------------------------------------------------
// attn v7e: v7d + softmax/PV overlap — P-write moved directly after exp2
// (its only dependency), and the row-sum (rs shfl chain + l accumulation)
// deferred until AFTER the PV MFMAs: the sum isn't needed until the next
// tile's defer-max branch, so its VALU+crosslane ops co-schedule with PV's
// MFMA pipe (m114). One barrier per tile, Vs[3], setprio on MFMA clusters.
// ---------------------------------------------------------------------------
__global__ __launch_bounds__(256) void attn_mfma(
    const short* __restrict__ qb, const short* __restrict__ kb,
    const short* __restrict__ vtg, const short* __restrict__ wb,
    float* __restrict__ out) {
  __shared__ __attribute__((aligned(16))) short Ks[3][64 * 128]; // swz256, 16KB ea
  __shared__ __attribute__((aligned(16))) short Vs[3][64 * 64];  // swz128, 8KB ea
  __shared__ __attribute__((aligned(16))) short Ps[64 * 64];     // swz128, 8KB

  const int tid = threadIdx.x, lane = tid & 63, w = tid >> 6;
  const int lin = blockIdx.y * 16 + blockIdx.x; // [0,512)
  const int xcd = lin & 7, slot = lin >> 3;     // slot [0,64)
  const int bh = xcd + 8 * (slot >> 4);         // 4 bh per XCD -> KV L2-resident
  const int px = slot & 15;
  const int qtA = px, qtB = 31 - px;
  const int cntA = qtA + 1;
  const int NT = 33;

  const int b = bh >> 4, h = bh & 15;
  const int c16 = lane & 15;
  const int g4 = lane >> 4;
  const int koff = g4 << 3;
  const int rg4 = g4 << 2;
  const int lbase = lane & 48;

  const short* kbh = kb + (size_t)bh * T * 128;
  const short* vbh = vtg + (size_t)bh * 64 * T;

  bf8v aqA[4], aqB[4], bwo[2][4];
  {
    const short* qA = qb + ((size_t)bh * T + qtA * 64 + w * 16 + c16) * 128;
    const short* qB = qb + ((size_t)bh * T + qtB * 64 + w * 16 + c16) * 128;
#pragma unroll
    for (int ks = 0; ks < 4; ++ks) {
      aqA[ks] = *(const bf8v*)(qA + ks * 32 + koff);
      aqB[ks] = *(const bf8v*)(qB + ks * 32 + koff);
    }
#pragma unroll
    for (int ks = 0; ks < 2; ++ks)
#pragma unroll
      for (int nt = 0; nt < 4; ++nt)
        bwo[ks][nt] = *(const bf8v*)(wb + OFF_O + (size_t)(nt * 16 + c16) * 64 +
                                     ks * 32 + koff);
  }

  auto ktile = [&](int gg) { return (gg < NT) ? ((gg < cntA) ? gg : gg - cntA) : 0; };

  auto stageK = [&](int gg) { // 4 gload_lds per wave
    const int jt = ktile(gg);
    const char* src = (const char*)(kbh + jt * 64 * 128);
    char* dst = (char*)&Ks[gg % 3][0];
#pragma unroll
    for (int p = 0; p < 4; ++p) {
      const int base = p * 256 + w * 64;
      gload_lds16(src + swz256((base + lane) * 16), dst + base * 16);
    }
  };
  auto stageV = [&](int gg) { // 2 gload_lds per wave
    const int jt = ktile(gg);
    char* dst = (char*)&Vs[gg % 3][0];
#pragma unroll
    for (int p = 0; p < 2; ++p) {
      const int base = p * 256 + w * 64;
      const int tb = swz128((base + lane) * 16);
      const int r = tb >> 7, cb = tb & 127;
      gload_lds16((const char*)vbh + ((size_t)r * T + jt * 64) * 2 + cb,
                  dst + base * 16);
    }
  };

  stageK(0);
  stageK(1);
  stageV(0);
  asm volatile("s_waitcnt vmcnt(6)" ::: "memory");
  HARD_BARRIER();

  int gg = 0;
  float* obase = out + (size_t)b * T * 1024 + h * 64;

  auto run_seg = [&](const int qt, const bf8v(&aq)[4]) {
    const int t0 = qt * 64;
    const int lrow = w * 16 + rg4;
    const int qglob = t0 + w * 16 + c16;

    f4v ctx[4];
    float m = -INFINITY, l = 0.f;
#pragma unroll
    for (int nt = 0; nt < 4; ++nt) ctx[nt] = z4();

    for (int jt = 0; jt <= qt; ++jt, ++gg) {
      const short* Kb = &Ks[gg % 3][0];
      const short* Vb = &Vs[gg % 3][0];
      stageK(gg + 2);
      stageV(gg + 1);

      const int j0 = jt * 64;
      const bool diag = (jt == qt);

      f4v s[4];
#pragma unroll
      for (int nt = 0; nt < 4; ++nt) s[nt] = z4();
      __builtin_amdgcn_s_setprio(1);
#pragma unroll
      for (int ks = 0; ks < 4; ++ks) {
#pragma unroll
        for (int nt = 0; nt < 4; ++nt) {
          bf8v bk = ldA256(Kb, nt * 16 + c16, ks * 32 + koff);
          s[nt] = MFMA16(bk, aq[ks], s[nt]); // A=K, B=Q (swapped)
        }
      }
      __builtin_amdgcn_s_setprio(0);

      if (diag) {
#pragma unroll
        for (int nt = 0; nt < 4; ++nt)
#pragma unroll
          for (int r = 0; r < 4; ++r)
            if (j0 + nt * 16 + rg4 + r > qglob) s[nt][r] = -INFINITY;
      }

      f4v mnt;
#pragma unroll
      for (int r = 0; r < 4; ++r)
        mnt[r] = fmaxf(fmaxf(s[0][r], s[1][r]), fmaxf(s[2][r], s[3][r]));
      float mx = fmaxf(fmaxf(mnt[0], mnt[1]), fmaxf(mnt[2], mnt[3]));
      mx = fmaxf(mx, __shfl_xor(mx, 16));
      mx = fmaxf(mx, __shfl_xor(mx, 32));

      if (__any(mx - m > 8.f)) {
        const float mn  = fmaxf(m, mx);
        const float scl = __builtin_amdgcn_exp2f(m - mn);
        l *= scl; m = mn;
        float sr[4];
#pragma unroll
        for (int r = 0; r < 4; ++r) sr[r] = __shfl(scl, lbase + rg4 + r);
#pragma unroll
        for (int nt = 0; nt < 4; ++nt)
#pragma unroll
          for (int r = 0; r < 4; ++r) ctx[nt][r] *= sr[r];
      }

#pragma unroll
      for (int nt = 0; nt < 4; ++nt)
#pragma unroll
        for (int r = 0; r < 4; ++r)
          s[nt][r] = __builtin_amdgcn_exp2f(s[nt][r] - m);

      // P -> LDS immediately after exp2 (ds_writes drain under the rest)
      {
        char* prow = (char*)Ps;
        const int rbase = (w * 16 + c16) * 128 + koff;
#pragma unroll
        for (int nt = 0; nt < 4; ++nt) {
          __hip_bfloat162 h0 = __float22bfloat162_rn(make_float2(s[nt][0], s[nt][1]));
          __hip_bfloat162 h1 = __float22bfloat162_rn(make_float2(s[nt][2], s[nt][3]));
          uint2 d;
          d.x = *(unsigned int*)&h0;
          d.y = *(unsigned int*)&h1;
          *(uint2*)(prow + swz128(rbase + nt * 32)) = d;
        }
      }

      // drain prev tile's loads (leaves this tile's 6 in flight), then barrier
      // so ALL waves' V(gg) chunks are landed before any PV read. Only barrier
      // per tile (Ks WAR safe: all QK(gg) done here; Vs[3] ring keeps staged
      // buffer 2 away from any reader).
      asm volatile("s_waitcnt vmcnt(6)" ::: "memory");
      HARD_BARRIER();

      __builtin_amdgcn_s_setprio(1);
#pragma unroll
      for (int ks = 0; ks < 2; ++ks) {
        bf8v pa = ldA128(Ps, w * 16 + c16, ks * 32 + koff);
#pragma unroll
        for (int nt = 0; nt < 4; ++nt) {
          bf8v vf = ldA128(Vb, nt * 16 + c16, ks * 32 + koff);
          ctx[nt] = MFMA16(pa, vf, ctx[nt]);
        }
      }
      __builtin_amdgcn_s_setprio(0);

      // deferred row-sum: VALU + crosslane overlap with the PV MFMAs above
      // (l is next needed at the NEXT tile's defer-max branch / epilogue)
      {
        f4v sv = s[0] + s[1] + s[2] + s[3];
        float rs = (sv[0] + sv[1]) + (sv[2] + sv[3]);
        rs += __shfl_xor(rs, 16);
        rs += __shfl_xor(rs, 32);
        l += rs;
      }
    }

    float linv[4];
#pragma unroll
    for (int r = 0; r < 4; ++r) linv[r] = 1.0f / __shfl(l, lbase + rg4 + r);
    f4v cn[4];
#pragma unroll
    for (int nt = 0; nt < 4; ++nt)
#pragma unroll
      for (int r = 0; r < 4; ++r) cn[nt][r] = ctx[nt][r] * linv[r];
#pragma unroll
    for (int nt = 0; nt < 4; ++nt) scat128(Ps, w * 16, lane, nt, cn[nt]);

    f4v o[4];
#pragma unroll
    for (int nt = 0; nt < 4; ++nt) o[nt] = z4();
#pragma unroll
    for (int ks = 0; ks < 2; ++ks) {
      bf8v pa = ldA128(Ps, w * 16 + c16, ks * 32 + koff);
#pragma unroll
      for (int nt = 0; nt < 4; ++nt) o[nt] = MFMA16(pa, bwo[ks][nt], o[nt]);
    }

#pragma unroll
    for (int nt = 0; nt < 4; ++nt) {
#pragma unroll
      for (int r = 0; r < 4; ++r)
        obase[(size_t)(t0 + lrow + r) * 1024 + nt * 16 + c16] = o[nt][r];
    }
  };

  run_seg(qtA, aqA);
  run_seg(qtB, aqB);
}

} // namespace

extern "C" void kernel_launch(void* const* d_in, const int* in_sizes, int n_in,
                              void* d_out, int out_size, void* d_ws, size_t ws_size,
                              hipStream_t stream) {
  (void)in_sizes; (void)n_in; (void)out_size; (void)ws_size;
  const float* x     = (const float*)d_in[0];
  const float* W_DQ  = (const float*)d_in[1];
  const float* W_UQ  = (const float*)d_in[2];
  const float* W_DKV = (const float*)d_in[3];
  const float* W_UKV = (const float*)d_in[4];
  const float* W_QR  = (const float*)d_in[5];
  const float* W_KR  = (const float*)d_in[6];
  const float* W_O   = (const float*)d_in[7];
  const float* qnw   = (const float*)d_in[8];
  const float* knw   = (const float*)d_in[9];
  float* out = (float*)d_out;

  short* ws = (short*)d_ws;
  short* xb  = ws;                          // 4,194,304
  short* qb  = ws + (size_t)4194304;        // 8,388,608
  short* kb  = ws + (size_t)12582912;       // 8,388,608
  short* vtg = ws + (size_t)20971520;       // 4,194,304
  short* wb  = ws + (size_t)25165824;       // 274,432

  cvt_all_kernel<<<4096 + W_TOTAL / 256, 256, 0, stream>>>(
      x, W_DQ, W_UQ, W_DKV, W_UKV, W_QR, W_KR, W_O, xb, wb);
  dim3 pgrid(T / 128, 32); // 128-row tiles
  proj_q_mfma<<<pgrid, 256, 0, stream>>>(xb, wb, qnw, qb);
  proj_kv_mfma<<<pgrid, 256, 0, stream>>>(xb, wb, knw, kb, vtg);
  dim3 agrid(16, 32); // paired q-tiles, uniform work
  attn_mfma<<<agrid, 256, 0, stream>>>(qb, kb, vtg, wb, out);
}

// Round 19
// 127.685 us; speedup vs baseline: 1.1431x; 1.0001x over previous
//
#include <hip/hip_runtime.h>
#include <hip/hip_bf16.h>
#include <math.h>

namespace {

constexpr int T  = 2048;
constexpr int HD = 64;
constexpr float EPS = 1.1920929e-07f;
// SCALE * log2(e), folded into q at proj_q write time -> attn softmax runs in exp2 domain
constexpr float PS = 0.125f * 1.44269504f;

// bf16 weight pool offsets (in elements)
constexpr int OFF_DQ  = 0;       // 512*64
constexpr int OFF_UQ  = 32768;   // 64*512
constexpr int OFF_DKV = 65536;   // 1024*64
constexpr int OFF_UKV = 131072;  // 128*1024
constexpr int OFF_QR  = 262144;  // 64*64
constexpr int OFF_KR  = 266240;  // 64*64
constexpr int OFF_O   = 270336;  // 64*64
constexpr int W_TOTAL = 274432;

typedef __attribute__((ext_vector_type(8))) short bf8v;  // 8 bf16 (4 VGPR)
typedef __attribute__((ext_vector_type(4))) float f4v;   // MFMA C/D

#define MFMA16(a, b, c) __builtin_amdgcn_mfma_f32_16x16x32_bf16((a), (b), (c), 0, 0, 0)

// full-strength barrier for raw s_barrier use (rule #18 class): compiler
// memory fences both sides so gload_lds issues can't be hoisted across.
#define HARD_BARRIER()                                   \
  do {                                                   \
    asm volatile("" ::: "memory");                       \
    __builtin_amdgcn_s_barrier();                        \
    asm volatile("" ::: "memory");                       \
    __builtin_amdgcn_sched_barrier(0);                   \
  } while (0)

__device__ __forceinline__ short f2bf(float f) {
  union { float f; unsigned u; } v; v.f = f;
  unsigned r = v.u + 0x7FFFu + ((v.u >> 16) & 1u); // RNE
  return (short)(r >> 16);
}

__device__ __forceinline__ f4v z4() { f4v z = {0.f, 0.f, 0.f, 0.f}; return z; }

// XOR swizzles: spread row-strided b128 accesses across banks (m214 pattern)
__device__ __forceinline__ int swz128(int b) { return b ^ (((b >> 7) & 7) << 4); }
__device__ __forceinline__ int swz256(int b) { return b ^ (((b >> 8) & 7) << 4); }

__device__ __forceinline__ bf8v ldA128(const short* lds, int row, int k) {
  return *(const bf8v*)((const char*)lds + swz128(row * 128 + k * 2));
}
__device__ __forceinline__ bf8v ldA256(const short* lds, int row, int k) {
  return *(const bf8v*)((const char*)lds + swz256(row * 256 + k * 2));
}

// scatter a 16x16 D-fragment (col=lane&15, row=(lane>>4)*4+r) as bf16 into LDS
__device__ __forceinline__ void scat128(short* lds, int row0, int lane, int nt, f4v v) {
  int col = nt * 16 + (lane & 15);
  int r0 = row0 + ((lane >> 4) << 2);
#pragma unroll
  for (int r = 0; r < 4; ++r)
    *(short*)((char*)lds + swz128((r0 + r) * 128 + col * 2)) = f2bf(v[r]);
}
__device__ __forceinline__ void scat256(short* lds, int row0, int lane, int col, f4v v) {
  int r0 = row0 + ((lane >> 4) << 2);
#pragma unroll
  for (int r = 0; r < 4; ++r)
    *(short*)((char*)lds + swz256((r0 + r) * 256 + col * 2)) = f2bf(v[r]);
}

// async global->LDS, 16B per lane; LDS dest wave-uniform base + lane*16
__device__ __forceinline__ void gload_lds16(const void* g, void* l) {
  __builtin_amdgcn_global_load_lds(
      (const __attribute__((address_space(1))) void*)g,
      (__attribute__((address_space(3))) void*)l, 16, 0, 0);
}

// ---------------------------------------------------------------------------
// combined conversion: blocks [0,2048) convert x (8 elems/thread, 16B coalesced
// writes — all 8 share one head since 8|64); [2048, 2048+1072) convert W.
// ---------------------------------------------------------------------------
__global__ __launch_bounds__(256) void cvt_all_kernel(
    const float* __restrict__ x, const float* __restrict__ W_DQ,
    const float* __restrict__ W_UQ, const float* __restrict__ W_DKV,
    const float* __restrict__ W_UKV, const float* __restrict__ W_QR,
    const float* __restrict__ W_KR, const float* __restrict__ W_O,
    short* __restrict__ xb, short* __restrict__ wb) {
  if (blockIdx.x < 2048) {
    int i = (blockIdx.x * 256 + threadIdx.x) * 8; // over x linear (B,T,D)
    float4 v0 = *(const float4*)(x + i);
    float4 v1 = *(const float4*)(x + i + 4);
    int d = i & 1023, t = (i >> 10) & 2047, b = i >> 21;
    int h = d >> 6, dd = d & 63;
    bf8v o;
    o[0] = f2bf(v0.x); o[1] = f2bf(v0.y); o[2] = f2bf(v0.z); o[3] = f2bf(v0.w);
    o[4] = f2bf(v1.x); o[5] = f2bf(v1.y); o[6] = f2bf(v1.z); o[7] = f2bf(v1.w);
    *(bf8v*)(xb + ((((size_t)b * 16 + h) * T + t) * 64 + dd)) = o;
  } else {
    int i = (blockIdx.x - 2048) * 256 + threadIdx.x;
    const float* src; int off;
    if      (i < 32768)  { src = W_DQ;  off = 0; }
    else if (i < 65536)  { src = W_UQ;  off = 32768; }
    else if (i < 131072) { src = W_DKV; off = 65536; }
    else if (i < 262144) { src = W_UKV; off = 131072; }
    else if (i < 266240) { src = W_QR;  off = 262144; }
    else if (i < 270336) { src = W_KR;  off = 266240; }
    else                 { src = W_O;   off = 270336; }
    wb[i] = f2bf(src[i - off]);
  }
}

// ---------------------------------------------------------------------------
// proj_q v2 (round-10 verbatim; __syncthreads-based, airtight)
// ---------------------------------------------------------------------------
__global__ __launch_bounds__(256) void proj_q_mfma(
    const short* __restrict__ xb, const short* __restrict__ wb,
    const float* __restrict__ qnw, short* __restrict__ qb) {
  __shared__ __attribute__((aligned(16))) short Xs[128 * 64];   // 16KB
  __shared__ __attribute__((aligned(16))) short Wd[2][64 * 64]; // 2x8KB
  __shared__ __attribute__((aligned(16))) short Wu[2][64 * 64]; // 2x8KB
  __shared__ __attribute__((aligned(16))) short Cs[128 * 64];   // 16KB

  const int tid = threadIdx.x, lane = tid & 63, w = tid >> 6;
  const int bh = blockIdx.y, t0 = blockIdx.x * 128;
  const int c16 = lane & 15;
  const int koff = (lane >> 4) << 3;

  auto stageWd = [&](int lc) {
    const char* src = (const char*)(wb + OFF_DQ + lc * 64 * 64);
    char* dst = (char*)&Wd[lc & 1][0];
#pragma unroll
    for (int p = 0; p < 2; ++p) {
      const int base = p * 256 + w * 64;
      gload_lds16(src + swz128((base + lane) * 16), dst + base * 16);
    }
  };
  auto stageWu = [&](int lc) {
    const char* src = (const char*)(wb + OFF_UQ + lc * 64);
    char* dst = (char*)&Wu[lc & 1][0];
#pragma unroll
    for (int p = 0; p < 2; ++p) {
      const int base = p * 256 + w * 64;
      const int lb = swz128((base + lane) * 16);
      gload_lds16(src + (size_t)(lb >> 7) * 1024 + (lb & 127), dst + base * 16);
    }
  };

  {
    const char* src = (const char*)(xb + ((size_t)bh * T + t0) * 64);
#pragma unroll
    for (int p = 0; p < 4; ++p) {
      const int base = p * 256 + w * 64;
      gload_lds16(src + swz128((base + lane) * 16), (char*)Xs + base * 16);
    }
  }
  stageWd(0);
  stageWu(0);
  __syncthreads();

  f4v acc[2][4];
#pragma unroll
  for (int rg = 0; rg < 2; ++rg)
#pragma unroll
    for (int nt = 0; nt < 4; ++nt) acc[rg][nt] = z4();

  for (int lc = 0; lc < 8; ++lc) {
    if (lc < 7) { stageWd(lc + 1); stageWu(lc + 1); }
    else {
      const char* src = (const char*)(wb + OFF_QR);
      char* dst = (char*)&Wd[0][0];
#pragma unroll
      for (int p = 0; p < 2; ++p) {
        const int base = p * 256 + w * 64;
        gload_lds16(src + swz128((base + lane) * 16), dst + base * 16);
      }
    }
    const short* Wdc = &Wd[lc & 1][0];
    const short* Wuc = &Wu[lc & 1][0];

    f4v cc[2][4];
#pragma unroll
    for (int rg = 0; rg < 2; ++rg)
#pragma unroll
      for (int nt = 0; nt < 4; ++nt) cc[rg][nt] = z4();
#pragma unroll
    for (int rg = 0; rg < 2; ++rg)
#pragma unroll
      for (int ks = 0; ks < 2; ++ks) {
        bf8v a = ldA128(Xs, w * 32 + rg * 16 + c16, ks * 32 + koff);
#pragma unroll
        for (int nt = 0; nt < 4; ++nt) {
          bf8v b = ldA128(Wdc, nt * 16 + c16, ks * 32 + koff);
          cc[rg][nt] = MFMA16(a, b, cc[rg][nt]);
        }
      }
#pragma unroll
    for (int rg = 0; rg < 2; ++rg)
#pragma unroll
      for (int nt = 0; nt < 4; ++nt) scat128(Cs, w * 32 + rg * 16, lane, nt, cc[rg][nt]);
#pragma unroll
    for (int rg = 0; rg < 2; ++rg)
#pragma unroll
      for (int ks = 0; ks < 2; ++ks) {
        bf8v a = ldA128(Cs, w * 32 + rg * 16 + c16, ks * 32 + koff);
#pragma unroll
        for (int nt = 0; nt < 4; ++nt) {
          bf8v b = ldA128(Wuc, nt * 16 + c16, ks * 32 + koff);
          acc[rg][nt] = MFMA16(a, b, acc[rg][nt]);
        }
      }
    __syncthreads();
  }

  float w4[4];
#pragma unroll
  for (int nt = 0; nt < 4; ++nt) w4[nt] = qnw[nt * 16 + c16] * PS;
#pragma unroll
  for (int rg = 0; rg < 2; ++rg)
#pragma unroll
    for (int r = 0; r < 4; ++r) {
      float ss = 0.f;
#pragma unroll
      for (int nt = 0; nt < 4; ++nt) ss += acc[rg][nt][r] * acc[rg][nt][r];
      ss += __shfl_xor(ss, 1, 16); ss += __shfl_xor(ss, 2, 16);
      ss += __shfl_xor(ss, 4, 16); ss += __shfl_xor(ss, 8, 16);
      float inv = rsqrtf(ss * (1.f / 64.f) + EPS);
#pragma unroll
      for (int nt = 0; nt < 4; ++nt) acc[rg][nt][r] *= inv * w4[nt];
    }

#pragma unroll
  for (int rg = 0; rg < 2; ++rg)
#pragma unroll
    for (int nt = 0; nt < 4; ++nt) scat128(Cs, w * 32 + rg * 16, lane, nt, acc[rg][nt]);

  f4v qr[2][4];
#pragma unroll
  for (int rg = 0; rg < 2; ++rg)
#pragma unroll
    for (int nt = 0; nt < 4; ++nt) qr[rg][nt] = z4();
#pragma unroll
  for (int rg = 0; rg < 2; ++rg)
#pragma unroll
    for (int ks = 0; ks < 2; ++ks) {
      bf8v a = ldA128(Cs, w * 32 + rg * 16 + c16, ks * 32 + koff);
#pragma unroll
      for (int nt = 0; nt < 4; ++nt) {
        bf8v b = ldA128(&Wd[0][0], nt * 16 + c16, ks * 32 + koff);
        qr[rg][nt] = MFMA16(a, b, qr[rg][nt]);
      }
    }
#pragma unroll
  for (int rg = 0; rg < 2; ++rg)
#pragma unroll
    for (int nt = 0; nt < 4; ++nt) scat128(Xs, w * 32 + rg * 16, lane, nt, qr[rg][nt]);
  __syncthreads();

  short* qdst = qb + ((size_t)bh * T + t0) * 128;
#pragma unroll
  for (int p = 0; p < 4; ++p) {
    int ci = tid + p * 256;
    int r = ci >> 3, c = (ci & 7) << 3;
    *(bf8v*)(qdst + (size_t)r * 128 + c) =
        *(const bf8v*)((const char*)Cs + swz128(ci * 16));
    *(bf8v*)(qdst + (size_t)r * 128 + 64 + c) =
        *(const bf8v*)((const char*)Xs + swz128(ci * 16));
  }
}

// ---------------------------------------------------------------------------
// proj_kv v2 (round-10 verbatim)
// ---------------------------------------------------------------------------
__global__ __launch_bounds__(256) void proj_kv_mfma(
    const short* __restrict__ xb, const short* __restrict__ wb,
    const float* __restrict__ knw, short* __restrict__ kb, short* __restrict__ vtg) {
  __shared__ __attribute__((aligned(16))) short Xs[128 * 64];    // 16KB
  __shared__ __attribute__((aligned(16))) short Wd[2][64 * 64];  // 2x8KB
  __shared__ __attribute__((aligned(16))) short Wu[2][128 * 64]; // 2x16KB (-> Ko 32KB)
  __shared__ __attribute__((aligned(16))) short Cs[128 * 64];    // 16KB (-> Vt)

  const int tid = threadIdx.x, lane = tid & 63, w = tid >> 6;
  const int bh = blockIdx.y, t0 = blockIdx.x * 128;
  const int c16 = lane & 15;
  const int g4 = lane >> 4;
  const int koff = g4 << 3;
  const int rg4 = g4 << 2;

  auto stageWd = [&](int lc) {
    const char* src = (const char*)(wb + OFF_DKV + lc * 64 * 64);
    char* dst = (char*)&Wd[lc & 1][0];
#pragma unroll
    for (int p = 0; p < 2; ++p) {
      const int base = p * 256 + w * 64;
      gload_lds16(src + swz128((base + lane) * 16), dst + base * 16);
    }
  };
  auto stageWu = [&](int lc) {
    const char* src = (const char*)(wb + OFF_UKV + lc * 64);
    char* dst = (char*)&Wu[lc & 1][0];
#pragma unroll
    for (int p = 0; p < 4; ++p) {
      const int base = p * 256 + w * 64;
      const int lb = swz128((base + lane) * 16);
      gload_lds16(src + (size_t)(lb >> 7) * 2048 + (lb & 127), dst + base * 16);
    }
  };

  {
    const char* src = (const char*)(xb + ((size_t)bh * T + t0) * 64);
#pragma unroll
    for (int p = 0; p < 4; ++p) {
      const int base = p * 256 + w * 64;
      gload_lds16(src + swz128((base + lane) * 16), (char*)Xs + base * 16);
    }
  }
  stageWd(0);
  stageWu(0);
  __syncthreads();

  f4v acc[2][8];
#pragma unroll
  for (int rg = 0; rg < 2; ++rg)
#pragma unroll
    for (int nt = 0; nt < 8; ++nt) acc[rg][nt] = z4();

  for (int lc = 0; lc < 16; ++lc) {
    if (lc < 15) { stageWd(lc + 1); stageWu(lc + 1); }
    else {
      const char* src = (const char*)(wb + OFF_KR);
      char* dst = (char*)&Wd[0][0];
#pragma unroll
      for (int p = 0; p < 2; ++p) {
        const int base = p * 256 + w * 64;
        gload_lds16(src + swz128((base + lane) * 16), dst + base * 16);
      }
    }
    const short* Wdc = &Wd[lc & 1][0];
    const short* Wuc = &Wu[lc & 1][0];

    f4v cc[2][4];
#pragma unroll
    for (int rg = 0; rg < 2; ++rg)
#pragma unroll
      for (int nt = 0; nt < 4; ++nt) cc[rg][nt] = z4();
#pragma unroll
    for (int rg = 0; rg < 2; ++rg)
#pragma unroll
      for (int ks = 0; ks < 2; ++ks) {
        bf8v a = ldA128(Xs, w * 32 + rg * 16 + c16, ks * 32 + koff);
#pragma unroll
        for (int nt = 0; nt < 4; ++nt) {
          bf8v b = ldA128(Wdc, nt * 16 + c16, ks * 32 + koff);
          cc[rg][nt] = MFMA16(a, b, cc[rg][nt]);
        }
      }
#pragma unroll
    for (int rg = 0; rg < 2; ++rg)
#pragma unroll
      for (int nt = 0; nt < 4; ++nt) scat128(Cs, w * 32 + rg * 16, lane, nt, cc[rg][nt]);
#pragma unroll
    for (int rg = 0; rg < 2; ++rg)
#pragma unroll
      for (int ks = 0; ks < 2; ++ks) {
        bf8v a = ldA128(Cs, w * 32 + rg * 16 + c16, ks * 32 + koff);
#pragma unroll
        for (int nt = 0; nt < 8; ++nt) {
          bf8v b = ldA128(Wuc, nt * 16 + c16, ks * 32 + koff);
          acc[rg][nt] = MFMA16(a, b, acc[rg][nt]);
        }
      }
    __syncthreads();
  }

  float w4[4];
#pragma unroll
  for (int nt = 0; nt < 4; ++nt) w4[nt] = knw[nt * 16 + c16];
#pragma unroll
  for (int rg = 0; rg < 2; ++rg)
#pragma unroll
    for (int r = 0; r < 4; ++r) {
      float ss = 0.f;
#pragma unroll
      for (int nt = 0; nt < 4; ++nt) ss += acc[rg][nt][r] * acc[rg][nt][r];
      ss += __shfl_xor(ss, 1, 16); ss += __shfl_xor(ss, 2, 16);
      ss += __shfl_xor(ss, 4, 16); ss += __shfl_xor(ss, 8, 16);
      float inv = rsqrtf(ss * (1.f / 64.f) + EPS);
#pragma unroll
      for (int nt = 0; nt < 4; ++nt) acc[rg][nt][r] *= inv * w4[nt];
    }

  short* Ko = &Wu[0][0];
#pragma unroll
  for (int rg = 0; rg < 2; ++rg)
#pragma unroll
    for (int nt = 0; nt < 4; ++nt)
      scat256(Ko, w * 32 + rg * 16, lane, nt * 16 + c16, acc[rg][nt]);

#pragma unroll
  for (int rg = 0; rg < 2; ++rg)
#pragma unroll
    for (int nt = 0; nt < 4; ++nt) {
      const int d = nt * 16 + c16;
      const int tc0 = w * 32 + rg * 16 + rg4;
#pragma unroll
      for (int r = 0; r < 4; ++r)
        *(short*)((char*)Cs + swz256(d * 256 + (tc0 + r) * 2)) =
            f2bf(acc[rg][4 + nt][r]);
    }

  f4v kr[2][4];
#pragma unroll
  for (int rg = 0; rg < 2; ++rg)
#pragma unroll
    for (int nt = 0; nt < 4; ++nt) kr[rg][nt] = z4();
#pragma unroll
  for (int rg = 0; rg < 2; ++rg)
#pragma unroll
    for (int ks = 0; ks < 2; ++ks) {
      bf8v a = ldA128(Xs, w * 32 + rg * 16 + c16, ks * 32 + koff);
#pragma unroll
      for (int nt = 0; nt < 4; ++nt) {
        bf8v b = ldA128(&Wd[0][0], nt * 16 + c16, ks * 32 + koff);
        kr[rg][nt] = MFMA16(a, b, kr[rg][nt]);
      }
    }
#pragma unroll
  for (int rg = 0; rg < 2; ++rg)
#pragma unroll
    for (int nt = 0; nt < 4; ++nt)
      scat256(Ko, w * 32 + rg * 16, lane, 64 + nt * 16 + c16, kr[rg][nt]);
  __syncthreads();

  short* kdst = kb + ((size_t)bh * T + t0) * 128;
#pragma unroll
  for (int p = 0; p < 8; ++p) {
    int ci = tid + p * 256;
    int r = ci >> 4, c = (ci & 15) << 3;
    *(bf8v*)(kdst + (size_t)r * 128 + c) =
        *(const bf8v*)((const char*)Ko + swz256(ci * 16));
  }
#pragma unroll
  for (int p = 0; p < 4; ++p) {
    int ci = tid + p * 256;
    int d = ci >> 4, c = (ci & 15) << 3;
    *(bf8v*)(vtg + ((size_t)bh * 64 + d) * T + t0 + c) =
        *(const bf8v*)((const char*)Cs + swz256(ci * 16));
  }
}

// ---------------------------------------------------------------------------
// attn v7e (round-18 verbatim — best measured): depth-2 counted-vmcnt
// pipeline, one barrier/tile (Vs[3]), setprio MFMA clusters, softmax/PV
// overlap with deferred row-sum.
// ---------------------------------------------------------------------------
__global__ __launch_bounds__(256) void attn_mfma(
    const short* __restrict__ qb, const short* __restrict__ kb,
    const short* __restrict__ vtg, const short* __restrict__ wb,
    float* __restrict__ out) {
  __shared__ __attribute__((aligned(16))) short Ks[3][64 * 128]; // swz256, 16KB ea
  __shared__ __attribute__((aligned(16))) short Vs[3][64 * 64];  // swz128, 8KB ea
  __shared__ __attribute__((aligned(16))) short Ps[64 * 64];     // swz128, 8KB

  const int tid = threadIdx.x, lane = tid & 63, w = tid >> 6;
  const int lin = blockIdx.y * 16 + blockIdx.x; // [0,512)
  const int xcd = lin & 7, slot = lin >> 3;     // slot [0,64)
  const int bh = xcd + 8 * (slot >> 4);         // 4 bh per XCD -> KV L2-resident
  const int px = slot & 15;
  const int qtA = px, qtB = 31 - px;
  const int cntA = qtA + 1;
  const int NT = 33;

  const int b = bh >> 4, h = bh & 15;
  const int c16 = lane & 15;
  const int g4 = lane >> 4;
  const int koff = g4 << 3;
  const int rg4 = g4 << 2;
  const int lbase = lane & 48;

  const short* kbh = kb + (size_t)bh * T * 128;
  const short* vbh = vtg + (size_t)bh * 64 * T;

  bf8v aqA[4], aqB[4], bwo[2][4];
  {
    const short* qA = qb + ((size_t)bh * T + qtA * 64 + w * 16 + c16) * 128;
    const short* qB = qb + ((size_t)bh * T + qtB * 64 + w * 16 + c16) * 128;
#pragma unroll
    for (int ks = 0; ks < 4; ++ks) {
      aqA[ks] = *(const bf8v*)(qA + ks * 32 + koff);
      aqB[ks] = *(const bf8v*)(qB + ks * 32 + koff);
    }
#pragma unroll
    for (int ks = 0; ks < 2; ++ks)
#pragma unroll
      for (int nt = 0; nt < 4; ++nt)
        bwo[ks][nt] = *(const bf8v*)(wb + OFF_O + (size_t)(nt * 16 + c16) * 64 +
                                     ks * 32 + koff);
  }

  auto ktile = [&](int gg) { return (gg < NT) ? ((gg < cntA) ? gg : gg - cntA) : 0; };

  auto stageK = [&](int gg) { // 4 gload_lds per wave
    const int jt = ktile(gg);
    const char* src = (const char*)(kbh + jt * 64 * 128);
    char* dst = (char*)&Ks[gg % 3][0];
#pragma unroll
    for (int p = 0; p < 4; ++p) {
      const int base = p * 256 + w * 64;
      gload_lds16(src + swz256((base + lane) * 16), dst + base * 16);
    }
  };
  auto stageV = [&](int gg) { // 2 gload_lds per wave
    const int jt = ktile(gg);
    char* dst = (char*)&Vs[gg % 3][0];
#pragma unroll
    for (int p = 0; p < 2; ++p) {
      const int base = p * 256 + w * 64;
      const int tb = swz128((base + lane) * 16);
      const int r = tb >> 7, cb = tb & 127;
      gload_lds16((const char*)vbh + ((size_t)r * T + jt * 64) * 2 + cb,
                  dst + base * 16);
    }
  };

  stageK(0);
  stageK(1);
  stageV(0);
  asm volatile("s_waitcnt vmcnt(6)" ::: "memory");
  HARD_BARRIER();

  int gg = 0;
  float* obase = out + (size_t)b * T * 1024 + h * 64;

  auto run_seg = [&](const int qt, const bf8v(&aq)[4]) {
    const int t0 = qt * 64;
    const int lrow = w * 16 + rg4;
    const int qglob = t0 + w * 16 + c16;

    f4v ctx[4];
    float m = -INFINITY, l = 0.f;
#pragma unroll
    for (int nt = 0; nt < 4; ++nt) ctx[nt] = z4();

    for (int jt = 0; jt <= qt; ++jt, ++gg) {
      const short* Kb = &Ks[gg % 3][0];
      const short* Vb = &Vs[gg % 3][0];
      stageK(gg + 2);
      stageV(gg + 1);

      const int j0 = jt * 64;
      const bool diag = (jt == qt);

      f4v s[4];
#pragma unroll
      for (int nt = 0; nt < 4; ++nt) s[nt] = z4();
      __builtin_amdgcn_s_setprio(1);
#pragma unroll
      for (int ks = 0; ks < 4; ++ks) {
#pragma unroll
        for (int nt = 0; nt < 4; ++nt) {
          bf8v bk = ldA256(Kb, nt * 16 + c16, ks * 32 + koff);
          s[nt] = MFMA16(bk, aq[ks], s[nt]); // A=K, B=Q (swapped)
        }
      }
      __builtin_amdgcn_s_setprio(0);

      if (diag) {
#pragma unroll
        for (int nt = 0; nt < 4; ++nt)
#pragma unroll
          for (int r = 0; r < 4; ++r)
            if (j0 + nt * 16 + rg4 + r > qglob) s[nt][r] = -INFINITY;
      }

      f4v mnt;
#pragma unroll
      for (int r = 0; r < 4; ++r)
        mnt[r] = fmaxf(fmaxf(s[0][r], s[1][r]), fmaxf(s[2][r], s[3][r]));
      float mx = fmaxf(fmaxf(mnt[0], mnt[1]), fmaxf(mnt[2], mnt[3]));
      mx = fmaxf(mx, __shfl_xor(mx, 16));
      mx = fmaxf(mx, __shfl_xor(mx, 32));

      if (__any(mx - m > 8.f)) {
        const float mn  = fmaxf(m, mx);
        const float scl = __builtin_amdgcn_exp2f(m - mn);
        l *= scl; m = mn;
        float sr[4];
#pragma unroll
        for (int r = 0; r < 4; ++r) sr[r] = __shfl(scl, lbase + rg4 + r);
#pragma unroll
        for (int nt = 0; nt < 4; ++nt)
#pragma unroll
          for (int r = 0; r < 4; ++r) ctx[nt][r] *= sr[r];
      }

#pragma unroll
      for (int nt = 0; nt < 4; ++nt)
#pragma unroll
        for (int r = 0; r < 4; ++r)
          s[nt][r] = __builtin_amdgcn_exp2f(s[nt][r] - m);

      // P -> LDS immediately after exp2 (ds_writes drain under the rest)
      {
        char* prow = (char*)Ps;
        const int rbase = (w * 16 + c16) * 128 + koff;
#pragma unroll
        for (int nt = 0; nt < 4; ++nt) {
          __hip_bfloat162 h0 = __float22bfloat162_rn(make_float2(s[nt][0], s[nt][1]));
          __hip_bfloat162 h1 = __float22bfloat162_rn(make_float2(s[nt][2], s[nt][3]));
          uint2 d;
          d.x = *(unsigned int*)&h0;
          d.y = *(unsigned int*)&h1;
          *(uint2*)(prow + swz128(rbase + nt * 32)) = d;
        }
      }

      // drain prev tile's loads (leaves this tile's 6 in flight), then barrier
      // so ALL waves' V(gg) chunks are landed before any PV read. Only barrier
      // per tile (Ks WAR safe: all QK(gg) done here; Vs[3] ring keeps staged
      // buffer 2 away from any reader).
      asm volatile("s_waitcnt vmcnt(6)" ::: "memory");
      HARD_BARRIER();

      __builtin_amdgcn_s_setprio(1);
#pragma unroll
      for (int ks = 0; ks < 2; ++ks) {
        bf8v pa = ldA128(Ps, w * 16 + c16, ks * 32 + koff);
#pragma unroll
        for (int nt = 0; nt < 4; ++nt) {
          bf8v vf = ldA128(Vb, nt * 16 + c16, ks * 32 + koff);
          ctx[nt] = MFMA16(pa, vf, ctx[nt]);
        }
      }
      __builtin_amdgcn_s_setprio(0);

      // deferred row-sum: VALU + crosslane overlap with the PV MFMAs above
      {
        f4v sv = s[0] + s[1] + s[2] + s[3];
        float rs = (sv[0] + sv[1]) + (sv[2] + sv[3]);
        rs += __shfl_xor(rs, 16);
        rs += __shfl_xor(rs, 32);
        l += rs;
      }
    }

    float linv[4];
#pragma unroll
    for (int r = 0; r < 4; ++r) linv[r] = 1.0f / __shfl(l, lbase + rg4 + r);
    f4v cn[4];
#pragma unroll
    for (int nt = 0; nt < 4; ++nt)
#pragma unroll
      for (int r = 0; r < 4; ++r) cn[nt][r] = ctx[nt][r] * linv[r];
#pragma unroll
    for (int nt = 0; nt < 4; ++nt) scat128(Ps, w * 16, lane, nt, cn[nt]);

    f4v o[4];
#pragma unroll
    for (int nt = 0; nt < 4; ++nt) o[nt] = z4();
#pragma unroll
    for (int ks = 0; ks < 2; ++ks) {
      bf8v pa = ldA128(Ps, w * 16 + c16, ks * 32 + koff);
#pragma unroll
      for (int nt = 0; nt < 4; ++nt) o[nt] = MFMA16(pa, bwo[ks][nt], o[nt]);
    }

#pragma unroll
    for (int nt = 0; nt < 4; ++nt) {
#pragma unroll
      for (int r = 0; r < 4; ++r)
        obase[(size_t)(t0 + lrow + r) * 1024 + nt * 16 + c16] = o[nt][r];
    }
  };

  run_seg(qtA, aqA);
  run_seg(qtB, aqB);
}

} // namespace

extern "C" void kernel_launch(void* const* d_in, const int* in_sizes, int n_in,
                              void* d_out, int out_size, void* d_ws, size_t ws_size,
                              hipStream_t stream) {
  (void)in_sizes; (void)n_in; (void)out_size; (void)ws_size;
  const float* x     = (const float*)d_in[0];
  const float* W_DQ  = (const float*)d_in[1];
  const float* W_UQ  = (const float*)d_in[2];
  const float* W_DKV = (const float*)d_in[3];
  const float* W_UKV = (const float*)d_in[4];
  const float* W_QR  = (const float*)d_in[5];
  const float* W_KR  = (const float*)d_in[6];
  const float* W_O   = (const float*)d_in[7];
  const float* qnw   = (const float*)d_in[8];
  const float* knw   = (const float*)d_in[9];
  float* out = (float*)d_out;

  short* ws = (short*)d_ws;
  short* xb  = ws;                          // 4,194,304
  short* qb  = ws + (size_t)4194304;        // 8,388,608
  short* kb  = ws + (size_t)12582912;       // 8,388,608
  short* vtg = ws + (size_t)20971520;       // 4,194,304
  short* wb  = ws + (size_t)25165824;       // 274,432

  cvt_all_kernel<<<2048 + W_TOTAL / 256, 256, 0, stream>>>(
      x, W_DQ, W_UQ, W_DKV, W_UKV, W_QR, W_KR, W_O, xb, wb);
  dim3 pgrid(T / 128, 32); // 128-row tiles
  proj_q_mfma<<<pgrid, 256, 0, stream>>>(xb, wb, qnw, qb);
  proj_kv_mfma<<<pgrid, 256, 0, stream>>>(xb, wb, knw, kb, vtg);
  dim3 agrid(16, 32); // paired q-tiles, uniform work
  attn_mfma<<<agrid, 256, 0, stream>>>(qb, kb, vtg, wb, out);
}